// Round 1
// baseline (3398.939 us; speedup 1.0000x reference)
//
#include <hip/hip_runtime.h>

#define LN2F 0.69314718055994530942f

__device__ __forceinline__ float ssp_f(float t){
  // softplus(t) - ln2, numerically stable
  return fmaxf(t, 0.0f) + __logf(1.0f + __expf(-fabsf(t))) - LN2F;
}

// ---------------- index width detection (int32 vs int64 edge_index) --------
__global__ void detect_idx_kernel(const unsigned* __restrict__ ei, int* __restrict__ flag){
  __shared__ int cnt;
  if (threadIdx.x == 0) cnt = 0;
  __syncthreads();
  int nz = 0;
  for (int i = threadIdx.x; i < 1024; i += 256)
    nz += (ei[2*i + 1] != 0u) ? 1 : 0;
  atomicAdd(&cnt, nz);
  __syncthreads();
  // int32 data: odd words are real indices (~all nonzero). int64: high words all 0.
  if (threadIdx.x == 0) *flag = (cnt > 64) ? 1 : 0;
}

__device__ __forceinline__ int load_idx(const void* ei, int is32, size_t pos){
  return is32 ? ((const int*)ei)[pos] : (int)(((const long long*)ei)[pos]);
}

// ---------------- shared GEMM tile: out[r][f] = sum_k A_s[r][k]*W[f][k] ----
// A_s: [64][132] activations (row stride 132 words, 16B aligned, broadcast reads)
// B_s: [128][36] weight chunk (row stride 36 = 4 mod 32 -> optimal 4-phase b128 reads)
// thread (fg,tr): rows r0..r0+7, cols f = fg + 32*j
__device__ __forceinline__ void gemm_tile(const float (&A_s)[64][132], float (&B_s)[128][36],
                                          const float* __restrict__ W, int fg, int r0,
                                          float acc[8][4]){
  #pragma unroll
  for (int r = 0; r < 8; ++r)
    #pragma unroll
    for (int j = 0; j < 4; ++j) acc[r][j] = 0.0f;
  for (int kc = 0; kc < 4; ++kc){
    __syncthreads();                       // previous users of B_s (and A_s writes) done
    const int t = threadIdx.x;
    #pragma unroll
    for (int q = t; q < 1024; q += 256){   // 4096 floats = 128 f x 32 k
      int f = q >> 3, kk = (q & 7) << 2;
      *(float4*)&B_s[f][kk] = *(const float4*)&W[f*128 + kc*32 + kk];
    }
    __syncthreads();
    #pragma unroll
    for (int kk4 = 0; kk4 < 8; ++kk4){
      float4 b0 = *(const float4*)&B_s[fg      ][kk4*4];
      float4 b1 = *(const float4*)&B_s[fg + 32 ][kk4*4];
      float4 b2 = *(const float4*)&B_s[fg + 64 ][kk4*4];
      float4 b3 = *(const float4*)&B_s[fg + 96 ][kk4*4];
      #pragma unroll
      for (int r = 0; r < 8; ++r){
        float4 a = *(const float4*)&A_s[r0 + r][kc*32 + kk4*4];
        acc[r][0] += a.x*b0.x + a.y*b0.y + a.z*b0.z + a.w*b0.w;
        acc[r][1] += a.x*b1.x + a.y*b1.y + a.z*b1.z + a.w*b1.w;
        acc[r][2] += a.x*b2.x + a.y*b2.y + a.z*b2.z + a.w*b2.w;
        acc[r][3] += a.x*b3.x + a.y*b3.y + a.z*b3.z + a.w*b3.w;
      }
    }
  }
}

// ---------------- kernel 1: h = ssp(xa W_diff^T + b), msged = ssp(xa W_same^T + b)
__global__ __launch_bounds__(256) void node_dual_kernel(
    const float* __restrict__ x, const float* __restrict__ Wsame, const float* __restrict__ bsame,
    const float* __restrict__ Wdiff, const float* __restrict__ bdiff,
    float* __restrict__ h, float* __restrict__ msged, int N){
  __shared__ float A_s[64][132];
  __shared__ float B_s[128][36];
  const int t = threadIdx.x;
  const int fg = t & 31, tr = t >> 5, r0 = tr * 8;
  const int row0 = blockIdx.x * 64;
  // stage A = ssp(x tile)
  #pragma unroll
  for (int q = t; q < 2048; q += 256){
    int row = q >> 5, c = (q & 31) << 2;
    float4 v = make_float4(0.f, 0.f, 0.f, 0.f);
    if (row0 + row < N) v = *(const float4*)&x[(size_t)(row0 + row)*128 + c];
    v.x = ssp_f(v.x); v.y = ssp_f(v.y); v.z = ssp_f(v.z); v.w = ssp_f(v.w);
    *(float4*)&A_s[row][c] = v;
  }
  float acc[8][4];
  gemm_tile(A_s, B_s, Wsame, fg, r0, acc);
  #pragma unroll
  for (int j = 0; j < 4; ++j){
    float bv = bsame[fg + 32*j];
    #pragma unroll
    for (int r = 0; r < 8; ++r){
      int gr = row0 + r0 + r;
      if (gr < N) msged[(size_t)gr*128 + fg + 32*j] = ssp_f(acc[r][j] + bv);
    }
  }
  gemm_tile(A_s, B_s, Wdiff, fg, r0, acc);
  #pragma unroll
  for (int j = 0; j < 4; ++j){
    float bv = bdiff[fg + 32*j];
    #pragma unroll
    for (int r = 0; r < 8; ++r){
      int gr = row0 + r0 + r;
      if (gr < N) h[(size_t)gr*128 + fg + 32*j] = ssp_f(acc[r][j] + bv);
    }
  }
}

// ---------------- kernel 2: gate = ea W_G^T ; atomic msged[dst] += h[src]*gate
__global__ __launch_bounds__(256) void edge_kernel(
    const float* __restrict__ ea, const void* __restrict__ ei, const int* __restrict__ flag,
    const float* __restrict__ WG, const float* __restrict__ h, float* __restrict__ msged,
    int E){
  __shared__ float WGs[64][128];   // [k][f]
  __shared__ float eas[64][68];    // [e_local][k]
  const int t = threadIdx.x;
  const int fg = t & 31, eg = t >> 5;
  const int f0 = fg << 2;
  const int is32 = *flag;
  for (int q = t; q < 8192; q += 256){ int f = q >> 6, k = q & 63; WGs[k][f] = WG[q]; }
  for (long long base = (long long)blockIdx.x * 64; base < E; base += (long long)gridDim.x * 64){
    __syncthreads();                       // previous eas readers done; also covers WGs staging
    #pragma unroll
    for (int q = t; q < 1024; q += 256){   // 64 edges x 64 attrs
      int e = q >> 4, kk = (q & 15) << 2;
      long long ge = base + e;
      float4 v = make_float4(0.f, 0.f, 0.f, 0.f);
      if (ge < E) v = *(const float4*)&ea[(size_t)ge*64 + kk];
      *(float4*)&eas[e][kk] = v;
    }
    __syncthreads();
    float acc[8][4];
    #pragma unroll
    for (int j = 0; j < 8; ++j){ acc[j][0]=0.f; acc[j][1]=0.f; acc[j][2]=0.f; acc[j][3]=0.f; }
    #pragma unroll
    for (int k4 = 0; k4 < 16; ++k4){
      float4 w0 = *(const float4*)&WGs[k4*4 + 0][f0];
      float4 w1 = *(const float4*)&WGs[k4*4 + 1][f0];
      float4 w2 = *(const float4*)&WGs[k4*4 + 2][f0];
      float4 w3 = *(const float4*)&WGs[k4*4 + 3][f0];
      #pragma unroll
      for (int j = 0; j < 8; ++j){
        float4 a = *(const float4*)&eas[eg*8 + j][k4*4];
        acc[j][0] += a.x*w0.x + a.y*w1.x + a.z*w2.x + a.w*w3.x;
        acc[j][1] += a.x*w0.y + a.y*w1.y + a.z*w2.y + a.w*w3.y;
        acc[j][2] += a.x*w0.z + a.y*w1.z + a.z*w2.z + a.w*w3.z;
        acc[j][3] += a.x*w0.w + a.y*w1.w + a.z*w2.w + a.w*w3.w;
      }
    }
    #pragma unroll
    for (int j = 0; j < 8; ++j){
      long long e = base + eg*8 + j;
      if (e < E){
        int s = load_idx(ei, is32, (size_t)e);
        int d = load_idx(ei, is32, (size_t)((long long)E + e));
        const float4 hv = *(const float4*)&h[(size_t)s*128 + f0];
        float* mp = &msged[(size_t)d*128 + f0];
        atomicAdd(mp + 0, acc[j][0]*hv.x);
        atomicAdd(mp + 1, acc[j][1]*hv.y);
        atomicAdd(mp + 2, acc[j][2]*hv.z);
        atomicAdd(mp + 3, acc[j][3]*hv.w);
      }
    }
  }
}

// ---------------- kernel 3: fused residual chain + final linear + skip ----
__global__ __launch_bounds__(256) void tail_kernel(
    const float* __restrict__ msged, const float* __restrict__ x, const float* __restrict__ u,
    const float* __restrict__ rW1, const float* __restrict__ rb1,
    const float* __restrict__ rW2, const float* __restrict__ rb2,
    const float* __restrict__ Wlast, const float* __restrict__ blast,
    float* __restrict__ out0, int N, int NRES){
  __shared__ float A_s[64][132];
  __shared__ float B_s[128][36];
  const int t = threadIdx.x;
  const int fg = t & 31, tr = t >> 5, r0 = tr * 8;
  const int row0 = blockIdx.x * 64;
  float treg[8][4];
  #pragma unroll
  for (int r = 0; r < 8; ++r){
    int gr = row0 + r0 + r;
    #pragma unroll
    for (int j = 0; j < 4; ++j)
      treg[r][j] = (gr < N) ? msged[(size_t)gr*128 + fg + 32*j] : 0.0f;
  }
  float acc[8][4];
  for (int l = 0; l < NRES; ++l){
    __syncthreads();                       // previous A_s readers done
    #pragma unroll
    for (int r = 0; r < 8; ++r)
      #pragma unroll
      for (int j = 0; j < 4; ++j) A_s[r0 + r][fg + 32*j] = ssp_f(treg[r][j]);
    gemm_tile(A_s, B_s, rW1 + (size_t)l*16384, fg, r0, acc);
    __syncthreads();                       // all reads of A_s done before overwrite
    #pragma unroll
    for (int j = 0; j < 4; ++j){
      float bv = rb1[l*128 + fg + 32*j];
      #pragma unroll
      for (int r = 0; r < 8; ++r) A_s[r0 + r][fg + 32*j] = ssp_f(acc[r][j] + bv);
    }
    gemm_tile(A_s, B_s, rW2 + (size_t)l*16384, fg, r0, acc);
    #pragma unroll
    for (int j = 0; j < 4; ++j){
      float bv = rb2[l*128 + fg + 32*j];
      #pragma unroll
      for (int r = 0; r < 8; ++r) treg[r][j] += acc[r][j] + bv;
    }
  }
  __syncthreads();
  #pragma unroll
  for (int r = 0; r < 8; ++r)
    #pragma unroll
    for (int j = 0; j < 4; ++j) A_s[r0 + r][fg + 32*j] = ssp_f(treg[r][j]);
  gemm_tile(A_s, B_s, Wlast, fg, r0, acc);
  #pragma unroll
  for (int j = 0; j < 4; ++j){
    float bv = blast[fg + 32*j];
    float uv = u[fg + 32*j];
    #pragma unroll
    for (int r = 0; r < 8; ++r){
      int gr = row0 + r0 + r;
      if (gr < N){
        size_t idx = (size_t)gr*128 + fg + 32*j;
        out0[idx] = acc[r][j] + bv + x[idx]*uv;
      }
    }
  }
}

extern "C" void kernel_launch(void* const* d_in, const int* in_sizes, int n_in,
                              void* d_out, int out_size, void* d_ws, size_t ws_size,
                              hipStream_t stream){
  const float* x     = (const float*)d_in[0];
  const void*  ei    = d_in[1];
  const float* ea    = (const float*)d_in[2];
  const float* Wsame = (const float*)d_in[3];
  const float* bsame = (const float*)d_in[4];
  const float* Wdiff = (const float*)d_in[5];
  const float* bdiff = (const float*)d_in[6];
  const float* WG    = (const float*)d_in[7];
  const float* rW1   = (const float*)d_in[8];
  const float* rb1   = (const float*)d_in[9];
  const float* rW2   = (const float*)d_in[10];
  const float* rb2   = (const float*)d_in[11];
  const float* Wlast = (const float*)d_in[12];
  const float* blast = (const float*)d_in[13];
  const float* u     = (const float*)d_in[14];

  const int N    = in_sizes[0] / 128;
  const int E    = in_sizes[1] / 2;
  const int NRES = in_sizes[8] / (128*128);

  float* out0  = (float*)d_out;
  float* msged = (float*)d_out + (size_t)N * 128;   // second output, used in place
  int*   flag  = (int*)d_ws;
  float* h     = (float*)((char*)d_ws + 256);       // N*128 floats

  const int nb_node = (N + 63) / 64;
  int nb_edge = (E + 63) / 64; if (nb_edge > 2048) nb_edge = 2048;

  detect_idx_kernel<<<1, 256, 0, stream>>>((const unsigned*)ei, flag);
  node_dual_kernel<<<nb_node, 256, 0, stream>>>(x, Wsame, bsame, Wdiff, bdiff, h, msged, N);
  edge_kernel<<<nb_edge, 256, 0, stream>>>(ea, ei, flag, WG, h, msged, E);
  tail_kernel<<<nb_node, 256, 0, stream>>>(msged, x, u, rW1, rb1, rW2, rb2, Wlast, blast,
                                           out0, N, NRES);
}

// Round 2
// 3018.227 us; speedup vs baseline: 1.1261x; 1.1261x over previous
//
#include <hip/hip_runtime.h>
#include <hip/hip_bf16.h>

#define LN2F 0.69314718055994530942f

__device__ __forceinline__ float ssp_f(float t){
  // softplus(t) - ln2, numerically stable
  return fmaxf(t, 0.0f) + __logf(1.0f + __expf(-fabsf(t))) - LN2F;
}
__device__ __forceinline__ unsigned short f2bf(float f){
  __hip_bfloat16 b = __float2bfloat16(f);
  return *reinterpret_cast<unsigned short*>(&b);
}
__device__ __forceinline__ float bf2f(unsigned short u){
  __hip_bfloat16 b = *reinterpret_cast<__hip_bfloat16*>(&u);
  return __bfloat162float(b);
}

// ---------------- index width detection (int32 vs int64 edge_index) --------
__global__ void detect_idx_kernel(const unsigned* __restrict__ ei, int* __restrict__ flag){
  __shared__ int cnt;
  if (threadIdx.x == 0) cnt = 0;
  __syncthreads();
  int nz = 0;
  for (int i = threadIdx.x; i < 1024; i += 256)
    nz += (ei[2*i + 1] != 0u) ? 1 : 0;
  atomicAdd(&cnt, nz);
  __syncthreads();
  // int32 data: odd words are real indices (~all nonzero). int64: high words all 0.
  if (threadIdx.x == 0) *flag = (cnt > 64) ? 1 : 0;
}

__device__ __forceinline__ int load_idx(const void* ei, int is32, size_t pos){
  return is32 ? ((const int*)ei)[pos] : (int)(((const long long*)ei)[pos]);
}

// ---------------- CSR build ------------------------------------------------
__global__ void zero_int_kernel(int* __restrict__ p, int n){
  int i = blockIdx.x * 256 + threadIdx.x;
  if (i < n) p[i] = 0;
}

__global__ void hist_kernel(const void* __restrict__ ei, const int* __restrict__ flag,
                            int* __restrict__ count, int E){
  const int is32 = *flag;
  for (long long e = (long long)blockIdx.x * 256 + threadIdx.x; e < E;
       e += (long long)gridDim.x * 256){
    int d = load_idx(ei, is32, (size_t)((long long)E + e));
    atomicAdd(&count[d], 1);
  }
}

__global__ __launch_bounds__(1024) void scan_kernel(const int* __restrict__ count,
                                                    int* __restrict__ offs,
                                                    int* __restrict__ cur, int N){
  __shared__ int buf[1024];
  __shared__ int carry;
  if (threadIdx.x == 0) carry = 0;
  __syncthreads();
  for (int base = 0; base < N; base += 1024){
    int i = base + threadIdx.x;
    int v = (i < N) ? count[i] : 0;
    buf[threadIdx.x] = v;
    __syncthreads();
    for (int off = 1; off < 1024; off <<= 1){
      int tv = (threadIdx.x >= off) ? buf[threadIdx.x - off] : 0;
      __syncthreads();
      buf[threadIdx.x] += tv;
      __syncthreads();
    }
    int exc = buf[threadIdx.x] - v + carry;   // carry = pre-chunk value
    if (i < N){ offs[i] = exc; cur[i] = exc; }
    __syncthreads();                          // everyone has read carry
    if (threadIdx.x == 1023) carry += buf[1023];
    __syncthreads();                          // carry visible for next chunk
  }
  if (threadIdx.x == 0) offs[N] = carry;
}

__global__ void fill_kernel(const void* __restrict__ ei, const int* __restrict__ flag,
                            int* __restrict__ cur, int* __restrict__ pos, int E){
  const int is32 = *flag;
  for (long long e = (long long)blockIdx.x * 256 + threadIdx.x; e < E;
       e += (long long)gridDim.x * 256){
    int d = load_idx(ei, is32, (size_t)((long long)E + e));
    pos[e] = atomicAdd(&cur[d], 1);
  }
}

// ---------------- shared GEMM tile: out[r][f] = sum_k A_s[r][k]*W[f][k] ----
__device__ __forceinline__ void gemm_tile(const float (&A_s)[64][132], float (&B_s)[128][36],
                                          const float* __restrict__ W, int fg, int r0,
                                          float acc[8][4]){
  #pragma unroll
  for (int r = 0; r < 8; ++r)
    #pragma unroll
    for (int j = 0; j < 4; ++j) acc[r][j] = 0.0f;
  for (int kc = 0; kc < 4; ++kc){
    __syncthreads();                       // previous users of B_s (and A_s writes) done
    const int t = threadIdx.x;
    #pragma unroll
    for (int q = t; q < 1024; q += 256){   // 4096 floats = 128 f x 32 k
      int f = q >> 3, kk = (q & 7) << 2;
      *(float4*)&B_s[f][kk] = *(const float4*)&W[f*128 + kc*32 + kk];
    }
    __syncthreads();
    #pragma unroll
    for (int kk4 = 0; kk4 < 8; ++kk4){
      float4 b0 = *(const float4*)&B_s[fg      ][kk4*4];
      float4 b1 = *(const float4*)&B_s[fg + 32 ][kk4*4];
      float4 b2 = *(const float4*)&B_s[fg + 64 ][kk4*4];
      float4 b3 = *(const float4*)&B_s[fg + 96 ][kk4*4];
      #pragma unroll
      for (int r = 0; r < 8; ++r){
        float4 a = *(const float4*)&A_s[r0 + r][kc*32 + kk4*4];
        acc[r][0] += a.x*b0.x + a.y*b0.y + a.z*b0.z + a.w*b0.w;
        acc[r][1] += a.x*b1.x + a.y*b1.y + a.z*b1.z + a.w*b1.w;
        acc[r][2] += a.x*b2.x + a.y*b2.y + a.z*b2.z + a.w*b2.w;
        acc[r][3] += a.x*b3.x + a.y*b3.y + a.z*b3.z + a.w*b3.w;
      }
    }
  }
}

// ---------------- kernel 1: h = ssp(xa W_diff^T + b), msged = ssp(xa W_same^T + b)
__global__ __launch_bounds__(256) void node_dual_kernel(
    const float* __restrict__ x, const float* __restrict__ Wsame, const float* __restrict__ bsame,
    const float* __restrict__ Wdiff, const float* __restrict__ bdiff,
    float* __restrict__ h, float* __restrict__ msged, int N){
  __shared__ float A_s[64][132];
  __shared__ float B_s[128][36];
  const int t = threadIdx.x;
  const int fg = t & 31, tr = t >> 5, r0 = tr * 8;
  const int row0 = blockIdx.x * 64;
  #pragma unroll
  for (int q = t; q < 2048; q += 256){
    int row = q >> 5, c = (q & 31) << 2;
    float4 v = make_float4(0.f, 0.f, 0.f, 0.f);
    if (row0 + row < N) v = *(const float4*)&x[(size_t)(row0 + row)*128 + c];
    v.x = ssp_f(v.x); v.y = ssp_f(v.y); v.z = ssp_f(v.z); v.w = ssp_f(v.w);
    *(float4*)&A_s[row][c] = v;
  }
  float acc[8][4];
  gemm_tile(A_s, B_s, Wsame, fg, r0, acc);
  #pragma unroll
  for (int j = 0; j < 4; ++j){
    float bv = bsame[fg + 32*j];
    #pragma unroll
    for (int r = 0; r < 8; ++r){
      int gr = row0 + r0 + r;
      if (gr < N) msged[(size_t)gr*128 + fg + 32*j] = ssp_f(acc[r][j] + bv);
    }
  }
  gemm_tile(A_s, B_s, Wdiff, fg, r0, acc);
  #pragma unroll
  for (int j = 0; j < 4; ++j){
    float bv = bdiff[fg + 32*j];
    #pragma unroll
    for (int r = 0; r < 8; ++r){
      int gr = row0 + r0 + r;
      if (gr < N) h[(size_t)gr*128 + fg + 32*j] = ssp_f(acc[r][j] + bv);
    }
  }
}

// ---------------- kernel 2a: msg[pos[e]] = bf16( h[src[e]] * (ea[e] @ WG^T) )
__global__ __launch_bounds__(256) void edge_msg_kernel(
    const float* __restrict__ ea, const void* __restrict__ ei, const int* __restrict__ flag,
    const float* __restrict__ WG, const float* __restrict__ h,
    const int* __restrict__ pos, unsigned short* __restrict__ msg, int E){
  __shared__ float WGs[64][132];   // [k][f], padded: staging conflict 64-way -> 8-way
  __shared__ float eas[64][68];    // [e_local][k]
  const int t = threadIdx.x;
  const int fg = t & 31, eg = t >> 5;
  const int f0 = fg << 2;
  const int is32 = *flag;
  const long long base = (long long)blockIdx.x * 64;
  for (int q = t; q < 8192; q += 256){ int f = q >> 6, k = q & 63; WGs[k][f] = WG[q]; }
  #pragma unroll
  for (int q = t; q < 1024; q += 256){   // 64 edges x 64 attrs
    int e = q >> 4, kk = (q & 15) << 2;
    long long ge = base + e;
    float4 v = make_float4(0.f, 0.f, 0.f, 0.f);
    if (ge < E) v = *(const float4*)&ea[(size_t)ge*64 + kk];
    *(float4*)&eas[e][kk] = v;
  }
  __syncthreads();
  float acc[8][4];
  #pragma unroll
  for (int j = 0; j < 8; ++j){ acc[j][0]=0.f; acc[j][1]=0.f; acc[j][2]=0.f; acc[j][3]=0.f; }
  #pragma unroll
  for (int k4 = 0; k4 < 16; ++k4){
    float4 w0 = *(const float4*)&WGs[k4*4 + 0][f0];
    float4 w1 = *(const float4*)&WGs[k4*4 + 1][f0];
    float4 w2 = *(const float4*)&WGs[k4*4 + 2][f0];
    float4 w3 = *(const float4*)&WGs[k4*4 + 3][f0];
    #pragma unroll
    for (int j = 0; j < 8; ++j){
      float4 a = *(const float4*)&eas[eg*8 + j][k4*4];
      acc[j][0] += a.x*w0.x + a.y*w1.x + a.z*w2.x + a.w*w3.x;
      acc[j][1] += a.x*w0.y + a.y*w1.y + a.z*w2.y + a.w*w3.y;
      acc[j][2] += a.x*w0.z + a.y*w1.z + a.z*w2.z + a.w*w3.z;
      acc[j][3] += a.x*w0.w + a.y*w1.w + a.z*w2.w + a.w*w3.w;
    }
  }
  #pragma unroll
  for (int j = 0; j < 8; ++j){
    long long e = base + eg*8 + j;
    if (e < E){
      int s = load_idx(ei, is32, (size_t)e);
      int p = pos[e];
      const float4 hv = *(const float4*)&h[(size_t)s*128 + f0];
      uint2 w;
      w.x = (unsigned)f2bf(acc[j][0]*hv.x) | ((unsigned)f2bf(acc[j][1]*hv.y) << 16);
      w.y = (unsigned)f2bf(acc[j][2]*hv.z) | ((unsigned)f2bf(acc[j][3]*hv.w) << 16);
      *(uint2*)&msg[(size_t)p*128 + f0] = w;
    }
  }
}

// ---------------- kernel 2b: msged[d] += sum of its contiguous CSR msg rows
__global__ __launch_bounds__(256) void gather_kernel(
    const unsigned short* __restrict__ msg, const int* __restrict__ offs,
    float* __restrict__ msged, int N){
  int wid = blockIdx.x * 4 + (threadIdx.x >> 6);   // one wave per dst row
  int lane = threadIdx.x & 63;
  if (wid >= N) return;
  int beg = offs[wid], end = offs[wid + 1];
  float sx = 0.f, sy = 0.f;
  for (int p = beg; p < end; ++p){
    unsigned v = *(const unsigned*)&msg[(size_t)p*128 + lane*2];
    sx += bf2f((unsigned short)(v & 0xffffu));
    sy += bf2f((unsigned short)(v >> 16));
  }
  float* mp = &msged[(size_t)wid*128 + lane*2];
  mp[0] += sx;
  mp[1] += sy;
}

// ---------------- fallback: atomic scatter (used only if ws too small) -----
__global__ __launch_bounds__(256) void edge_kernel(
    const float* __restrict__ ea, const void* __restrict__ ei, const int* __restrict__ flag,
    const float* __restrict__ WG, const float* __restrict__ h, float* __restrict__ msged,
    int E){
  __shared__ float WGs[64][132];
  __shared__ float eas[64][68];
  const int t = threadIdx.x;
  const int fg = t & 31, eg = t >> 5;
  const int f0 = fg << 2;
  const int is32 = *flag;
  for (int q = t; q < 8192; q += 256){ int f = q >> 6, k = q & 63; WGs[k][f] = WG[q]; }
  for (long long base = (long long)blockIdx.x * 64; base < E; base += (long long)gridDim.x * 64){
    __syncthreads();
    #pragma unroll
    for (int q = t; q < 1024; q += 256){
      int e = q >> 4, kk = (q & 15) << 2;
      long long ge = base + e;
      float4 v = make_float4(0.f, 0.f, 0.f, 0.f);
      if (ge < E) v = *(const float4*)&ea[(size_t)ge*64 + kk];
      *(float4*)&eas[e][kk] = v;
    }
    __syncthreads();
    float acc[8][4];
    #pragma unroll
    for (int j = 0; j < 8; ++j){ acc[j][0]=0.f; acc[j][1]=0.f; acc[j][2]=0.f; acc[j][3]=0.f; }
    #pragma unroll
    for (int k4 = 0; k4 < 16; ++k4){
      float4 w0 = *(const float4*)&WGs[k4*4 + 0][f0];
      float4 w1 = *(const float4*)&WGs[k4*4 + 1][f0];
      float4 w2 = *(const float4*)&WGs[k4*4 + 2][f0];
      float4 w3 = *(const float4*)&WGs[k4*4 + 3][f0];
      #pragma unroll
      for (int j = 0; j < 8; ++j){
        float4 a = *(const float4*)&eas[eg*8 + j][k4*4];
        acc[j][0] += a.x*w0.x + a.y*w1.x + a.z*w2.x + a.w*w3.x;
        acc[j][1] += a.x*w0.y + a.y*w1.y + a.z*w2.y + a.w*w3.y;
        acc[j][2] += a.x*w0.z + a.y*w1.z + a.z*w2.z + a.w*w3.z;
        acc[j][3] += a.x*w0.w + a.y*w1.w + a.z*w2.w + a.w*w3.w;
      }
    }
    #pragma unroll
    for (int j = 0; j < 8; ++j){
      long long e = base + eg*8 + j;
      if (e < E){
        int s = load_idx(ei, is32, (size_t)e);
        int d = load_idx(ei, is32, (size_t)((long long)E + e));
        const float4 hv = *(const float4*)&h[(size_t)s*128 + f0];
        float* mp = &msged[(size_t)d*128 + f0];
        atomicAdd(mp + 0, acc[j][0]*hv.x);
        atomicAdd(mp + 1, acc[j][1]*hv.y);
        atomicAdd(mp + 2, acc[j][2]*hv.z);
        atomicAdd(mp + 3, acc[j][3]*hv.w);
      }
    }
  }
}

// ---------------- kernel 3: fused residual chain + final linear + skip ----
__global__ __launch_bounds__(256) void tail_kernel(
    const float* __restrict__ msged, const float* __restrict__ x, const float* __restrict__ u,
    const float* __restrict__ rW1, const float* __restrict__ rb1,
    const float* __restrict__ rW2, const float* __restrict__ rb2,
    const float* __restrict__ Wlast, const float* __restrict__ blast,
    float* __restrict__ out0, int N, int NRES){
  __shared__ float A_s[64][132];
  __shared__ float B_s[128][36];
  const int t = threadIdx.x;
  const int fg = t & 31, tr = t >> 5, r0 = tr * 8;
  const int row0 = blockIdx.x * 64;
  float treg[8][4];
  #pragma unroll
  for (int r = 0; r < 8; ++r){
    int gr = row0 + r0 + r;
    #pragma unroll
    for (int j = 0; j < 4; ++j)
      treg[r][j] = (gr < N) ? msged[(size_t)gr*128 + fg + 32*j] : 0.0f;
  }
  float acc[8][4];
  for (int l = 0; l < NRES; ++l){
    __syncthreads();
    #pragma unroll
    for (int r = 0; r < 8; ++r)
      #pragma unroll
      for (int j = 0; j < 4; ++j) A_s[r0 + r][fg + 32*j] = ssp_f(treg[r][j]);
    gemm_tile(A_s, B_s, rW1 + (size_t)l*16384, fg, r0, acc);
    __syncthreads();
    #pragma unroll
    for (int j = 0; j < 4; ++j){
      float bv = rb1[l*128 + fg + 32*j];
      #pragma unroll
      for (int r = 0; r < 8; ++r) A_s[r0 + r][fg + 32*j] = ssp_f(acc[r][j] + bv);
    }
    gemm_tile(A_s, B_s, rW2 + (size_t)l*16384, fg, r0, acc);
    #pragma unroll
    for (int j = 0; j < 4; ++j){
      float bv = rb2[l*128 + fg + 32*j];
      #pragma unroll
      for (int r = 0; r < 8; ++r) treg[r][j] += acc[r][j] + bv;
    }
  }
  __syncthreads();
  #pragma unroll
  for (int r = 0; r < 8; ++r)
    #pragma unroll
    for (int j = 0; j < 4; ++j) A_s[r0 + r][fg + 32*j] = ssp_f(treg[r][j]);
  gemm_tile(A_s, B_s, Wlast, fg, r0, acc);
  #pragma unroll
  for (int j = 0; j < 4; ++j){
    float bv = blast[fg + 32*j];
    float uv = u[fg + 32*j];
    #pragma unroll
    for (int r = 0; r < 8; ++r){
      int gr = row0 + r0 + r;
      if (gr < N){
        size_t idx = (size_t)gr*128 + fg + 32*j;
        out0[idx] = acc[r][j] + bv + x[idx]*uv;
      }
    }
  }
}

extern "C" void kernel_launch(void* const* d_in, const int* in_sizes, int n_in,
                              void* d_out, int out_size, void* d_ws, size_t ws_size,
                              hipStream_t stream){
  const float* x     = (const float*)d_in[0];
  const void*  ei    = d_in[1];
  const float* ea    = (const float*)d_in[2];
  const float* Wsame = (const float*)d_in[3];
  const float* bsame = (const float*)d_in[4];
  const float* Wdiff = (const float*)d_in[5];
  const float* bdiff = (const float*)d_in[6];
  const float* WG    = (const float*)d_in[7];
  const float* rW1   = (const float*)d_in[8];
  const float* rb1   = (const float*)d_in[9];
  const float* rW2   = (const float*)d_in[10];
  const float* rb2   = (const float*)d_in[11];
  const float* Wlast = (const float*)d_in[12];
  const float* blast = (const float*)d_in[13];
  const float* u     = (const float*)d_in[14];

  const int N    = in_sizes[0] / 128;
  const int E    = in_sizes[1] / 2;
  const int NRES = in_sizes[8] / (128*128);

  float* out0  = (float*)d_out;
  float* msged = (float*)d_out + (size_t)N * 128;   // second output, built in place

  auto align256 = [](size_t v){ return (v + 255) & ~(size_t)255; };
  const size_t o_h     = 256;
  const size_t o_count = align256(o_h     + (size_t)N * 128 * 4);
  const size_t o_off   = align256(o_count + (size_t)N * 4);
  const size_t o_cur   = align256(o_off   + (size_t)(N + 1) * 4);
  const size_t o_pos   = align256(o_cur   + (size_t)N * 4);
  const size_t o_msg   = align256(o_pos   + (size_t)E * 4);
  const size_t need    = o_msg + (size_t)E * 128 * 2;

  int*   flag = (int*)d_ws;
  float* h    = (float*)((char*)d_ws + o_h);

  const int nb_node = (N + 63) / 64;

  detect_idx_kernel<<<1, 256, 0, stream>>>((const unsigned*)ei, flag);
  node_dual_kernel<<<nb_node, 256, 0, stream>>>(x, Wsame, bsame, Wdiff, bdiff, h, msged, N);

  if (ws_size >= need){
    int* count = (int*)((char*)d_ws + o_count);
    int* offs  = (int*)((char*)d_ws + o_off);
    int* cur   = (int*)((char*)d_ws + o_cur);
    int* pos   = (int*)((char*)d_ws + o_pos);
    unsigned short* msg = (unsigned short*)((char*)d_ws + o_msg);

    zero_int_kernel<<<(N + 255) / 256, 256, 0, stream>>>(count, N);
    hist_kernel<<<1024, 256, 0, stream>>>(ei, flag, count, E);
    scan_kernel<<<1, 1024, 0, stream>>>(count, offs, cur, N);
    fill_kernel<<<1024, 256, 0, stream>>>(ei, flag, cur, pos, E);

    const int nb_edge = (E + 63) / 64;
    edge_msg_kernel<<<nb_edge, 256, 0, stream>>>(ea, ei, flag, WG, h, pos, msg, E);
    gather_kernel<<<(N + 3) / 4, 256, 0, stream>>>(msg, offs, msged, N);
  } else {
    int nb_edge = (E + 63) / 64; if (nb_edge > 2048) nb_edge = 2048;
    edge_kernel<<<nb_edge, 256, 0, stream>>>(ea, ei, flag, WG, h, msged, E);
  }

  tail_kernel<<<nb_node, 256, 0, stream>>>(msged, x, u, rW1, rb1, rW2, rb2, Wlast, blast,
                                           out0, N, NRES);
}

// Round 3
// 2814.609 us; speedup vs baseline: 1.2076x; 1.0723x over previous
//
#include <hip/hip_runtime.h>
#include <hip/hip_bf16.h>

#define LN2F 0.69314718055994530942f

__device__ __forceinline__ float ssp_f(float t){
  // softplus(t) - ln2, numerically stable
  return fmaxf(t, 0.0f) + __logf(1.0f + __expf(-fabsf(t))) - LN2F;
}
__device__ __forceinline__ unsigned short f2bf(float f){
  __hip_bfloat16 b = __float2bfloat16(f);
  return *reinterpret_cast<unsigned short*>(&b);
}
__device__ __forceinline__ float bf2f(unsigned short u){
  __hip_bfloat16 b = *reinterpret_cast<__hip_bfloat16*>(&u);
  return __bfloat162float(b);
}

// ---------------- index width detection (int32 vs int64 edge_index) --------
__global__ void detect_idx_kernel(const unsigned* __restrict__ ei, int* __restrict__ flag){
  __shared__ int cnt;
  if (threadIdx.x == 0) cnt = 0;
  __syncthreads();
  int nz = 0;
  for (int i = threadIdx.x; i < 1024; i += 256)
    nz += (ei[2*i + 1] != 0u) ? 1 : 0;
  atomicAdd(&cnt, nz);
  __syncthreads();
  // int32 data: odd words are real indices (~all nonzero). int64: high words all 0.
  if (threadIdx.x == 0) *flag = (cnt > 64) ? 1 : 0;
}

__device__ __forceinline__ int load_idx(const void* ei, int is32, size_t pos){
  return is32 ? ((const int*)ei)[pos] : (int)(((const long long*)ei)[pos]);
}

// ---------------- CSR build ------------------------------------------------
__global__ void zero_int_kernel(int* __restrict__ p, int n){
  int i = blockIdx.x * 256 + threadIdx.x;
  if (i < n) p[i] = 0;
}

__global__ void hist_kernel(const void* __restrict__ ei, const int* __restrict__ flag,
                            int* __restrict__ count, int E){
  const int is32 = *flag;
  for (long long e = (long long)blockIdx.x * 256 + threadIdx.x; e < E;
       e += (long long)gridDim.x * 256){
    int d = load_idx(ei, is32, (size_t)((long long)E + e));
    atomicAdd(&count[d], 1);
  }
}

__global__ __launch_bounds__(1024) void scan_kernel(const int* __restrict__ count,
                                                    int* __restrict__ offs,
                                                    int* __restrict__ cur, int N){
  __shared__ int buf[1024];
  __shared__ int carry_s;
  if (threadIdx.x == 0) carry_s = 0;
  __syncthreads();
  for (int base = 0; base < N; base += 8192){
    int v[8];
    int i0 = base + threadIdx.x * 8;
    int s = 0;
    #pragma unroll
    for (int r = 0; r < 8; ++r){ int i = i0 + r; v[r] = (i < N) ? count[i] : 0; s += v[r]; }
    buf[threadIdx.x] = s;
    __syncthreads();
    #pragma unroll
    for (int off = 1; off < 1024; off <<= 1){
      int tv = (threadIdx.x >= off) ? buf[threadIdx.x - off] : 0;
      __syncthreads();
      buf[threadIdx.x] += tv;
      __syncthreads();
    }
    int run = buf[threadIdx.x] - s + carry_s;   // exclusive prefix for this thread's chunk
    #pragma unroll
    for (int r = 0; r < 8; ++r){
      int i = i0 + r;
      if (i < N){ offs[i] = run; cur[i] = run; }
      run += v[r];
    }
    __syncthreads();                          // all reads of carry_s done
    if (threadIdx.x == 1023) carry_s += buf[1023];
    __syncthreads();                          // carry visible for next chunk
  }
  if (threadIdx.x == 0) offs[N] = carry_s;
}

// perm[slot] = e : sequential slots map to (random) edges
__global__ void fill_kernel(const void* __restrict__ ei, const int* __restrict__ flag,
                            int* __restrict__ cur, int* __restrict__ perm, int E){
  const int is32 = *flag;
  for (long long e = (long long)blockIdx.x * 256 + threadIdx.x; e < E;
       e += (long long)gridDim.x * 256){
    int d = load_idx(ei, is32, (size_t)((long long)E + e));
    int slot = atomicAdd(&cur[d], 1);
    perm[slot] = (int)e;
  }
}

// ---------------- shared GEMM tile: out[r][f] = sum_k A_s[r][k]*W[f][k] ----
__device__ __forceinline__ void gemm_tile(const float (&A_s)[64][132], float (&B_s)[128][36],
                                          const float* __restrict__ W, int fg, int r0,
                                          float acc[8][4]){
  #pragma unroll
  for (int r = 0; r < 8; ++r)
    #pragma unroll
    for (int j = 0; j < 4; ++j) acc[r][j] = 0.0f;
  for (int kc = 0; kc < 4; ++kc){
    __syncthreads();                       // previous users of B_s (and A_s writes) done
    const int t = threadIdx.x;
    #pragma unroll
    for (int q = t; q < 1024; q += 256){   // 4096 floats = 128 f x 32 k
      int f = q >> 3, kk = (q & 7) << 2;
      *(float4*)&B_s[f][kk] = *(const float4*)&W[f*128 + kc*32 + kk];
    }
    __syncthreads();
    #pragma unroll
    for (int kk4 = 0; kk4 < 8; ++kk4){
      float4 b0 = *(const float4*)&B_s[fg      ][kk4*4];
      float4 b1 = *(const float4*)&B_s[fg + 32 ][kk4*4];
      float4 b2 = *(const float4*)&B_s[fg + 64 ][kk4*4];
      float4 b3 = *(const float4*)&B_s[fg + 96 ][kk4*4];
      #pragma unroll
      for (int r = 0; r < 8; ++r){
        float4 a = *(const float4*)&A_s[r0 + r][kc*32 + kk4*4];
        acc[r][0] += a.x*b0.x + a.y*b0.y + a.z*b0.z + a.w*b0.w;
        acc[r][1] += a.x*b1.x + a.y*b1.y + a.z*b1.z + a.w*b1.w;
        acc[r][2] += a.x*b2.x + a.y*b2.y + a.z*b2.z + a.w*b2.w;
        acc[r][3] += a.x*b3.x + a.y*b3.y + a.z*b3.z + a.w*b3.w;
      }
    }
  }
}

// ---------------- kernel 1: h = ssp(xa W_diff^T + b), msged = ssp(xa W_same^T + b)
__global__ __launch_bounds__(256) void node_dual_kernel(
    const float* __restrict__ x, const float* __restrict__ Wsame, const float* __restrict__ bsame,
    const float* __restrict__ Wdiff, const float* __restrict__ bdiff,
    float* __restrict__ h, float* __restrict__ msged, int N){
  __shared__ float A_s[64][132];
  __shared__ float B_s[128][36];
  const int t = threadIdx.x;
  const int fg = t & 31, tr = t >> 5, r0 = tr * 8;
  const int row0 = blockIdx.x * 64;
  #pragma unroll
  for (int q = t; q < 2048; q += 256){
    int row = q >> 5, c = (q & 31) << 2;
    float4 v = make_float4(0.f, 0.f, 0.f, 0.f);
    if (row0 + row < N) v = *(const float4*)&x[(size_t)(row0 + row)*128 + c];
    v.x = ssp_f(v.x); v.y = ssp_f(v.y); v.z = ssp_f(v.z); v.w = ssp_f(v.w);
    *(float4*)&A_s[row][c] = v;
  }
  float acc[8][4];
  gemm_tile(A_s, B_s, Wsame, fg, r0, acc);
  #pragma unroll
  for (int j = 0; j < 4; ++j){
    float bv = bsame[fg + 32*j];
    #pragma unroll
    for (int r = 0; r < 8; ++r){
      int gr = row0 + r0 + r;
      if (gr < N) msged[(size_t)gr*128 + fg + 32*j] = ssp_f(acc[r][j] + bv);
    }
  }
  gemm_tile(A_s, B_s, Wdiff, fg, r0, acc);
  #pragma unroll
  for (int j = 0; j < 4; ++j){
    float bv = bdiff[fg + 32*j];
    #pragma unroll
    for (int r = 0; r < 8; ++r){
      int gr = row0 + r0 + r;
      if (gr < N) h[(size_t)gr*128 + fg + 32*j] = ssp_f(acc[r][j] + bv);
    }
  }
}

// ---------------- kernel 2a (sorted): for slot s in tile:
//   e = perm[s]; msg[s] = bf16( h[src[e]] * (ea[e] @ WG^T) )  -- sequential writes
__global__ __launch_bounds__(256) void edge_msg_kernel(
    const float* __restrict__ ea, const void* __restrict__ ei, const int* __restrict__ flag,
    const float* __restrict__ WG, const float* __restrict__ h,
    const int* __restrict__ perm, unsigned short* __restrict__ msg, int E){
  __shared__ float WGs[64][132];   // [k][f]
  __shared__ float eas[64][68];    // [slot_local][k]
  __shared__ int e_s[64];
  __shared__ int src_s[64];
  const int t = threadIdx.x;
  const int fg = t & 31, eg = t >> 5;
  const int f0 = fg << 2;
  const int is32 = *flag;
  const long long base = (long long)blockIdx.x * 64;
  for (int q = t; q < 8192; q += 256){ int f = q >> 6, k = q & 63; WGs[k][f] = WG[q]; }
  if (t < 64){
    long long slot = base + t;
    int e = (slot < (long long)E) ? perm[slot] : -1;
    e_s[t] = e;
    src_s[t] = (e >= 0) ? load_idx(ei, is32, (size_t)e) : 0;
  }
  __syncthreads();
  #pragma unroll
  for (int q = t; q < 1024; q += 256){   // 64 slots x 64 attrs, gathered rows
    int sl = q >> 4, kk = (q & 15) << 2;
    int e = e_s[sl];
    float4 v = make_float4(0.f, 0.f, 0.f, 0.f);
    if (e >= 0) v = *(const float4*)&ea[(size_t)e*64 + kk];
    *(float4*)&eas[sl][kk] = v;
  }
  __syncthreads();
  float acc[8][4];
  #pragma unroll
  for (int j = 0; j < 8; ++j){ acc[j][0]=0.f; acc[j][1]=0.f; acc[j][2]=0.f; acc[j][3]=0.f; }
  #pragma unroll
  for (int k4 = 0; k4 < 16; ++k4){
    float4 w0 = *(const float4*)&WGs[k4*4 + 0][f0];
    float4 w1 = *(const float4*)&WGs[k4*4 + 1][f0];
    float4 w2 = *(const float4*)&WGs[k4*4 + 2][f0];
    float4 w3 = *(const float4*)&WGs[k4*4 + 3][f0];
    #pragma unroll
    for (int j = 0; j < 8; ++j){
      float4 a = *(const float4*)&eas[eg*8 + j][k4*4];
      acc[j][0] += a.x*w0.x + a.y*w1.x + a.z*w2.x + a.w*w3.x;
      acc[j][1] += a.x*w0.y + a.y*w1.y + a.z*w2.y + a.w*w3.y;
      acc[j][2] += a.x*w0.z + a.y*w1.z + a.z*w2.z + a.w*w3.z;
      acc[j][3] += a.x*w0.w + a.y*w1.w + a.z*w2.w + a.w*w3.w;
    }
  }
  #pragma unroll
  for (int j = 0; j < 8; ++j){
    int sl = eg*8 + j;
    long long slot = base + sl;
    if (slot < (long long)E){
      int s = src_s[sl];
      const float4 hv = *(const float4*)&h[(size_t)s*128 + f0];
      uint2 w;
      w.x = (unsigned)f2bf(acc[j][0]*hv.x) | ((unsigned)f2bf(acc[j][1]*hv.y) << 16);
      w.y = (unsigned)f2bf(acc[j][2]*hv.z) | ((unsigned)f2bf(acc[j][3]*hv.w) << 16);
      *(uint2*)&msg[(size_t)slot*128 + f0] = w;   // sequential within the tile
    }
  }
}

// ---------------- kernel 2b: msged[d] += sum of its contiguous CSR msg rows
__global__ __launch_bounds__(256) void gather_kernel(
    const unsigned short* __restrict__ msg, const int* __restrict__ offs,
    float* __restrict__ msged, int N){
  int wid = blockIdx.x * 4 + (threadIdx.x >> 6);   // one wave per dst row
  int lane = threadIdx.x & 63;
  if (wid >= N) return;
  int beg = offs[wid], end = offs[wid + 1];
  float sx = 0.f, sy = 0.f;
  for (int p = beg; p < end; ++p){
    unsigned v = *(const unsigned*)&msg[(size_t)p*128 + lane*2];
    sx += bf2f((unsigned short)(v & 0xffffu));
    sy += bf2f((unsigned short)(v >> 16));
  }
  float* mp = &msged[(size_t)wid*128 + lane*2];
  mp[0] += sx;
  mp[1] += sy;
}

// ---------------- fallback: atomic scatter (used only if ws too small) -----
__global__ __launch_bounds__(256) void edge_kernel(
    const float* __restrict__ ea, const void* __restrict__ ei, const int* __restrict__ flag,
    const float* __restrict__ WG, const float* __restrict__ h, float* __restrict__ msged,
    int E){
  __shared__ float WGs[64][132];
  __shared__ float eas[64][68];
  const int t = threadIdx.x;
  const int fg = t & 31, eg = t >> 5;
  const int f0 = fg << 2;
  const int is32 = *flag;
  for (int q = t; q < 8192; q += 256){ int f = q >> 6, k = q & 63; WGs[k][f] = WG[q]; }
  for (long long base = (long long)blockIdx.x * 64; base < E; base += (long long)gridDim.x * 64){
    __syncthreads();
    #pragma unroll
    for (int q = t; q < 1024; q += 256){
      int e = q >> 4, kk = (q & 15) << 2;
      long long ge = base + e;
      float4 v = make_float4(0.f, 0.f, 0.f, 0.f);
      if (ge < E) v = *(const float4*)&ea[(size_t)ge*64 + kk];
      *(float4*)&eas[e][kk] = v;
    }
    __syncthreads();
    float acc[8][4];
    #pragma unroll
    for (int j = 0; j < 8; ++j){ acc[j][0]=0.f; acc[j][1]=0.f; acc[j][2]=0.f; acc[j][3]=0.f; }
    #pragma unroll
    for (int k4 = 0; k4 < 16; ++k4){
      float4 w0 = *(const float4*)&WGs[k4*4 + 0][f0];
      float4 w1 = *(const float4*)&WGs[k4*4 + 1][f0];
      float4 w2 = *(const float4*)&WGs[k4*4 + 2][f0];
      float4 w3 = *(const float4*)&WGs[k4*4 + 3][f0];
      #pragma unroll
      for (int j = 0; j < 8; ++j){
        float4 a = *(const float4*)&eas[eg*8 + j][k4*4];
        acc[j][0] += a.x*w0.x + a.y*w1.x + a.z*w2.x + a.w*w3.x;
        acc[j][1] += a.x*w0.y + a.y*w1.y + a.z*w2.y + a.w*w3.y;
        acc[j][2] += a.x*w0.z + a.y*w1.z + a.z*w2.z + a.w*w3.z;
        acc[j][3] += a.x*w0.w + a.y*w1.w + a.z*w2.w + a.w*w3.w;
      }
    }
    #pragma unroll
    for (int j = 0; j < 8; ++j){
      long long e = base + eg*8 + j;
      if (e < E){
        int s = load_idx(ei, is32, (size_t)e);
        int d = load_idx(ei, is32, (size_t)((long long)E + e));
        const float4 hv = *(const float4*)&h[(size_t)s*128 + f0];
        float* mp = &msged[(size_t)d*128 + f0];
        atomicAdd(mp + 0, acc[j][0]*hv.x);
        atomicAdd(mp + 1, acc[j][1]*hv.y);
        atomicAdd(mp + 2, acc[j][2]*hv.z);
        atomicAdd(mp + 3, acc[j][3]*hv.w);
      }
    }
  }
}

// ---------------- kernel 3: fused residual chain + final linear + skip ----
__global__ __launch_bounds__(256) void tail_kernel(
    const float* __restrict__ msged, const float* __restrict__ x, const float* __restrict__ u,
    const float* __restrict__ rW1, const float* __restrict__ rb1,
    const float* __restrict__ rW2, const float* __restrict__ rb2,
    const float* __restrict__ Wlast, const float* __restrict__ blast,
    float* __restrict__ out0, int N, int NRES){
  __shared__ float A_s[64][132];
  __shared__ float B_s[128][36];
  const int t = threadIdx.x;
  const int fg = t & 31, tr = t >> 5, r0 = tr * 8;
  const int row0 = blockIdx.x * 64;
  float treg[8][4];
  #pragma unroll
  for (int r = 0; r < 8; ++r){
    int gr = row0 + r0 + r;
    #pragma unroll
    for (int j = 0; j < 4; ++j)
      treg[r][j] = (gr < N) ? msged[(size_t)gr*128 + fg + 32*j] : 0.0f;
  }
  float acc[8][4];
  for (int l = 0; l < NRES; ++l){
    __syncthreads();
    #pragma unroll
    for (int r = 0; r < 8; ++r)
      #pragma unroll
      for (int j = 0; j < 4; ++j) A_s[r0 + r][fg + 32*j] = ssp_f(treg[r][j]);
    gemm_tile(A_s, B_s, rW1 + (size_t)l*16384, fg, r0, acc);
    __syncthreads();
    #pragma unroll
    for (int j = 0; j < 4; ++j){
      float bv = rb1[l*128 + fg + 32*j];
      #pragma unroll
      for (int r = 0; r < 8; ++r) A_s[r0 + r][fg + 32*j] = ssp_f(acc[r][j] + bv);
    }
    gemm_tile(A_s, B_s, rW2 + (size_t)l*16384, fg, r0, acc);
    #pragma unroll
    for (int j = 0; j < 4; ++j){
      float bv = rb2[l*128 + fg + 32*j];
      #pragma unroll
      for (int r = 0; r < 8; ++r) treg[r][j] += acc[r][j] + bv;
    }
  }
  __syncthreads();
  #pragma unroll
  for (int r = 0; r < 8; ++r)
    #pragma unroll
    for (int j = 0; j < 4; ++j) A_s[r0 + r][fg + 32*j] = ssp_f(treg[r][j]);
  gemm_tile(A_s, B_s, Wlast, fg, r0, acc);
  #pragma unroll
  for (int j = 0; j < 4; ++j){
    float bv = blast[fg + 32*j];
    float uv = u[fg + 32*j];
    #pragma unroll
    for (int r = 0; r < 8; ++r){
      int gr = row0 + r0 + r;
      if (gr < N){
        size_t idx = (size_t)gr*128 + fg + 32*j;
        out0[idx] = acc[r][j] + bv + x[idx]*uv;
      }
    }
  }
}

extern "C" void kernel_launch(void* const* d_in, const int* in_sizes, int n_in,
                              void* d_out, int out_size, void* d_ws, size_t ws_size,
                              hipStream_t stream){
  const float* x     = (const float*)d_in[0];
  const void*  ei    = d_in[1];
  const float* ea    = (const float*)d_in[2];
  const float* Wsame = (const float*)d_in[3];
  const float* bsame = (const float*)d_in[4];
  const float* Wdiff = (const float*)d_in[5];
  const float* bdiff = (const float*)d_in[6];
  const float* WG    = (const float*)d_in[7];
  const float* rW1   = (const float*)d_in[8];
  const float* rb1   = (const float*)d_in[9];
  const float* rW2   = (const float*)d_in[10];
  const float* rb2   = (const float*)d_in[11];
  const float* Wlast = (const float*)d_in[12];
  const float* blast = (const float*)d_in[13];
  const float* u     = (const float*)d_in[14];

  const int N    = in_sizes[0] / 128;
  const int E    = in_sizes[1] / 2;
  const int NRES = in_sizes[8] / (128*128);

  float* out0  = (float*)d_out;
  float* msged = (float*)d_out + (size_t)N * 128;   // second output, built in place

  auto align256 = [](size_t v){ return (v + 255) & ~(size_t)255; };
  const size_t o_h     = 256;
  const size_t o_count = align256(o_h     + (size_t)N * 128 * 4);
  const size_t o_off   = align256(o_count + (size_t)N * 4);
  const size_t o_cur   = align256(o_off   + (size_t)(N + 1) * 4);
  const size_t o_perm  = align256(o_cur   + (size_t)N * 4);
  const size_t o_msg   = align256(o_perm  + (size_t)E * 4);
  const size_t need    = o_msg + (size_t)E * 128 * 2;

  int*   flag = (int*)d_ws;
  float* h    = (float*)((char*)d_ws + o_h);

  const int nb_node = (N + 63) / 64;

  detect_idx_kernel<<<1, 256, 0, stream>>>((const unsigned*)ei, flag);
  node_dual_kernel<<<nb_node, 256, 0, stream>>>(x, Wsame, bsame, Wdiff, bdiff, h, msged, N);

  if (ws_size >= need){
    int* count = (int*)((char*)d_ws + o_count);
    int* offs  = (int*)((char*)d_ws + o_off);
    int* cur   = (int*)((char*)d_ws + o_cur);
    int* perm  = (int*)((char*)d_ws + o_perm);
    unsigned short* msg = (unsigned short*)((char*)d_ws + o_msg);

    zero_int_kernel<<<(N + 255) / 256, 256, 0, stream>>>(count, N);
    hist_kernel<<<1024, 256, 0, stream>>>(ei, flag, count, E);
    scan_kernel<<<1, 1024, 0, stream>>>(count, offs, cur, N);
    fill_kernel<<<1024, 256, 0, stream>>>(ei, flag, cur, perm, E);

    const int nb_edge = (E + 63) / 64;
    edge_msg_kernel<<<nb_edge, 256, 0, stream>>>(ea, ei, flag, WG, h, perm, msg, E);
    gather_kernel<<<(N + 3) / 4, 256, 0, stream>>>(msg, offs, msged, N);
  } else {
    int nb_edge = (E + 63) / 64; if (nb_edge > 2048) nb_edge = 2048;
    edge_kernel<<<nb_edge, 256, 0, stream>>>(ea, ei, flag, WG, h, msged, E);
  }

  tail_kernel<<<nb_node, 256, 0, stream>>>(msged, x, u, rW1, rb1, rW2, rb2, Wlast, blast,
                                           out0, N, NRES);
}

// Round 4
// 1388.526 us; speedup vs baseline: 2.4479x; 2.0270x over previous
//
#include <hip/hip_runtime.h>
#include <hip/hip_bf16.h>

#define LN2F 0.69314718055994530942f

__device__ __forceinline__ float ssp_f(float t){
  // softplus(t) - ln2, numerically stable
  return fmaxf(t, 0.0f) + __logf(1.0f + __expf(-fabsf(t))) - LN2F;
}

// ---------------- index width detection (int32 vs int64 edge_index) --------
__global__ void detect_idx_kernel(const unsigned* __restrict__ ei, int* __restrict__ flag){
  __shared__ int cnt;
  if (threadIdx.x == 0) cnt = 0;
  __syncthreads();
  int nz = 0;
  for (int i = threadIdx.x; i < 1024; i += 256)
    nz += (ei[2*i + 1] != 0u) ? 1 : 0;
  atomicAdd(&cnt, nz);
  __syncthreads();
  // int32 data: odd words are real indices (~all nonzero). int64: high words all 0.
  if (threadIdx.x == 0) *flag = (cnt > 64) ? 1 : 0;
}

__device__ __forceinline__ int load_idx(const void* ei, int is32, size_t pos){
  return is32 ? ((const int*)ei)[pos] : (int)(((const long long*)ei)[pos]);
}

// ---------------- CSR build ------------------------------------------------
__global__ void zero_int_kernel(int* __restrict__ p, int n){
  int i = blockIdx.x * 256 + threadIdx.x;
  if (i < n) p[i] = 0;
}

__global__ void hist_kernel(const void* __restrict__ ei, const int* __restrict__ flag,
                            int* __restrict__ count, int E){
  const int is32 = *flag;
  for (long long e = (long long)blockIdx.x * 256 + threadIdx.x; e < E;
       e += (long long)gridDim.x * 256){
    int d = load_idx(ei, is32, (size_t)((long long)E + e));
    atomicAdd(&count[d], 1);
  }
}

__global__ __launch_bounds__(1024) void scan_kernel(const int* __restrict__ count,
                                                    int* __restrict__ offs,
                                                    int* __restrict__ cur, int N){
  __shared__ int buf[1024];
  __shared__ int carry_s;
  if (threadIdx.x == 0) carry_s = 0;
  __syncthreads();
  for (int base = 0; base < N; base += 8192){
    int v[8];
    int i0 = base + threadIdx.x * 8;
    int s = 0;
    #pragma unroll
    for (int r = 0; r < 8; ++r){ int i = i0 + r; v[r] = (i < N) ? count[i] : 0; s += v[r]; }
    buf[threadIdx.x] = s;
    __syncthreads();
    #pragma unroll
    for (int off = 1; off < 1024; off <<= 1){
      int tv = (threadIdx.x >= off) ? buf[threadIdx.x - off] : 0;
      __syncthreads();
      buf[threadIdx.x] += tv;
      __syncthreads();
    }
    int run = buf[threadIdx.x] - s + carry_s;   // exclusive prefix for this thread's chunk
    #pragma unroll
    for (int r = 0; r < 8; ++r){
      int i = i0 + r;
      if (i < N){ offs[i] = run; cur[i] = run; }
      run += v[r];
    }
    __syncthreads();                          // all reads of carry_s done
    if (threadIdx.x == 1023) carry_s += buf[1023];
    __syncthreads();                          // carry visible for next chunk
  }
  if (threadIdx.x == 0) offs[N] = carry_s;
}

// perm[slot] = e : sequential slots (sorted by dst) map to edges
__global__ void fill_kernel(const void* __restrict__ ei, const int* __restrict__ flag,
                            int* __restrict__ cur, int* __restrict__ perm, int E){
  const int is32 = *flag;
  for (long long e = (long long)blockIdx.x * 256 + threadIdx.x; e < E;
       e += (long long)gridDim.x * 256){
    int d = load_idx(ei, is32, (size_t)((long long)E + e));
    int slot = atomicAdd(&cur[d], 1);
    perm[slot] = (int)e;
  }
}

// ---------------- shared GEMM tile: out[r][f] = sum_k A_s[r][k]*W[f][k] ----
__device__ __forceinline__ void gemm_tile(const float (&A_s)[64][132], float (&B_s)[128][36],
                                          const float* __restrict__ W, int fg, int r0,
                                          float acc[8][4]){
  #pragma unroll
  for (int r = 0; r < 8; ++r)
    #pragma unroll
    for (int j = 0; j < 4; ++j) acc[r][j] = 0.0f;
  for (int kc = 0; kc < 4; ++kc){
    __syncthreads();                       // previous users of B_s (and A_s writes) done
    const int t = threadIdx.x;
    #pragma unroll
    for (int q = t; q < 1024; q += 256){   // 4096 floats = 128 f x 32 k
      int f = q >> 3, kk = (q & 7) << 2;
      *(float4*)&B_s[f][kk] = *(const float4*)&W[f*128 + kc*32 + kk];
    }
    __syncthreads();
    #pragma unroll
    for (int kk4 = 0; kk4 < 8; ++kk4){
      float4 b0 = *(const float4*)&B_s[fg      ][kk4*4];
      float4 b1 = *(const float4*)&B_s[fg + 32 ][kk4*4];
      float4 b2 = *(const float4*)&B_s[fg + 64 ][kk4*4];
      float4 b3 = *(const float4*)&B_s[fg + 96 ][kk4*4];
      #pragma unroll
      for (int r = 0; r < 8; ++r){
        float4 a = *(const float4*)&A_s[r0 + r][kc*32 + kk4*4];
        acc[r][0] += a.x*b0.x + a.y*b0.y + a.z*b0.z + a.w*b0.w;
        acc[r][1] += a.x*b1.x + a.y*b1.y + a.z*b1.z + a.w*b1.w;
        acc[r][2] += a.x*b2.x + a.y*b2.y + a.z*b2.z + a.w*b2.w;
        acc[r][3] += a.x*b3.x + a.y*b3.y + a.z*b3.z + a.w*b3.w;
      }
    }
  }
}

// ---------------- kernel 1: h = ssp(xa W_diff^T + b), msged = ssp(xa W_same^T + b)
__global__ __launch_bounds__(256) void node_dual_kernel(
    const float* __restrict__ x, const float* __restrict__ Wsame, const float* __restrict__ bsame,
    const float* __restrict__ Wdiff, const float* __restrict__ bdiff,
    float* __restrict__ h, float* __restrict__ msged, int N){
  __shared__ float A_s[64][132];
  __shared__ float B_s[128][36];
  const int t = threadIdx.x;
  const int fg = t & 31, tr = t >> 5, r0 = tr * 8;
  const int row0 = blockIdx.x * 64;
  #pragma unroll
  for (int q = t; q < 2048; q += 256){
    int row = q >> 5, c = (q & 31) << 2;
    float4 v = make_float4(0.f, 0.f, 0.f, 0.f);
    if (row0 + row < N) v = *(const float4*)&x[(size_t)(row0 + row)*128 + c];
    v.x = ssp_f(v.x); v.y = ssp_f(v.y); v.z = ssp_f(v.z); v.w = ssp_f(v.w);
    *(float4*)&A_s[row][c] = v;
  }
  float acc[8][4];
  gemm_tile(A_s, B_s, Wsame, fg, r0, acc);
  #pragma unroll
  for (int j = 0; j < 4; ++j){
    float bv = bsame[fg + 32*j];
    #pragma unroll
    for (int r = 0; r < 8; ++r){
      int gr = row0 + r0 + r;
      if (gr < N) msged[(size_t)gr*128 + fg + 32*j] = ssp_f(acc[r][j] + bv);
    }
  }
  gemm_tile(A_s, B_s, Wdiff, fg, r0, acc);
  #pragma unroll
  for (int j = 0; j < 4; ++j){
    float bv = bdiff[fg + 32*j];
    #pragma unroll
    for (int r = 0; r < 8; ++r){
      int gr = row0 + r0 + r;
      if (gr < N) h[(size_t)gr*128 + fg + 32*j] = ssp_f(acc[r][j] + bv);
    }
  }
}

// ---------------- fused edge phase: per (dst, feature-half) wave ----------
// msged[d][f] += sum_{p in [offs[d],offs[d+1])} (ea[perm[p]] . WG[f][:]) * h[src][f]
__global__ __launch_bounds__(256) void edge_reduce_kernel(
    const float* __restrict__ ea, const void* __restrict__ ei, const int* __restrict__ flag,
    const float* __restrict__ WG, const float* __restrict__ h,
    const int* __restrict__ perm, const int* __restrict__ offs,
    float* __restrict__ msged, int N, int E){
  const int is32 = *flag;
  const int wave  = blockIdx.x * 4 + (threadIdx.x >> 6);
  const int lane  = threadIdx.x & 63;
  const int half  = wave & 1;                 // feature half: [0,64) or [64,128)
  const int f     = half * 64 + lane;
  const int nhw   = (gridDim.x * 4) >> 1;     // waves per half

  // preload this lane's WG row into registers (reused across all its dsts/edges)
  float wreg[64];
  #pragma unroll
  for (int k4 = 0; k4 < 16; ++k4){
    float4 v = *(const float4*)&WG[(size_t)f*64 + k4*4];
    wreg[k4*4+0]=v.x; wreg[k4*4+1]=v.y; wreg[k4*4+2]=v.z; wreg[k4*4+3]=v.w;
  }

  for (int d = wave >> 1; d < N; d += nhw){
    const int beg = offs[d], end = offs[d+1];
    float acc = 0.f;
    for (int p = beg; p < end; ++p){
      int e = perm[p];
      e = __builtin_amdgcn_readfirstlane(e);            // wave-uniform -> scalar loads
      int s = load_idx(ei, is32, (size_t)e);
      s = __builtin_amdgcn_readfirstlane(s);
      const float* __restrict__ earow = &ea[(size_t)e*64];
      float gate = 0.f;
      #pragma unroll
      for (int k = 0; k < 64; ++k) gate = __builtin_fmaf(earow[k], wreg[k], gate);
      float hv = h[(size_t)s*128 + f];                  // coalesced 256B row half
      acc = __builtin_fmaf(gate, hv, acc);
    }
    msged[(size_t)d*128 + f] += acc;                    // owner-exclusive, non-atomic
  }
}

// ---------------- kernel 3: fused residual chain + final linear + skip ----
__global__ __launch_bounds__(256) void tail_kernel(
    const float* __restrict__ msged, const float* __restrict__ x, const float* __restrict__ u,
    const float* __restrict__ rW1, const float* __restrict__ rb1,
    const float* __restrict__ rW2, const float* __restrict__ rb2,
    const float* __restrict__ Wlast, const float* __restrict__ blast,
    float* __restrict__ out0, int N, int NRES){
  __shared__ float A_s[64][132];
  __shared__ float B_s[128][36];
  const int t = threadIdx.x;
  const int fg = t & 31, tr = t >> 5, r0 = tr * 8;
  const int row0 = blockIdx.x * 64;
  float treg[8][4];
  #pragma unroll
  for (int r = 0; r < 8; ++r){
    int gr = row0 + r0 + r;
    #pragma unroll
    for (int j = 0; j < 4; ++j)
      treg[r][j] = (gr < N) ? msged[(size_t)gr*128 + fg + 32*j] : 0.0f;
  }
  float acc[8][4];
  for (int l = 0; l < NRES; ++l){
    __syncthreads();
    #pragma unroll
    for (int r = 0; r < 8; ++r)
      #pragma unroll
      for (int j = 0; j < 4; ++j) A_s[r0 + r][fg + 32*j] = ssp_f(treg[r][j]);
    gemm_tile(A_s, B_s, rW1 + (size_t)l*16384, fg, r0, acc);
    __syncthreads();
    #pragma unroll
    for (int j = 0; j < 4; ++j){
      float bv = rb1[l*128 + fg + 32*j];
      #pragma unroll
      for (int r = 0; r < 8; ++r) A_s[r0 + r][fg + 32*j] = ssp_f(acc[r][j] + bv);
    }
    gemm_tile(A_s, B_s, rW2 + (size_t)l*16384, fg, r0, acc);
    #pragma unroll
    for (int j = 0; j < 4; ++j){
      float bv = rb2[l*128 + fg + 32*j];
      #pragma unroll
      for (int r = 0; r < 8; ++r) treg[r][j] += acc[r][j] + bv;
    }
  }
  __syncthreads();
  #pragma unroll
  for (int r = 0; r < 8; ++r)
    #pragma unroll
    for (int j = 0; j < 4; ++j) A_s[r0 + r][fg + 32*j] = ssp_f(treg[r][j]);
  gemm_tile(A_s, B_s, Wlast, fg, r0, acc);
  #pragma unroll
  for (int j = 0; j < 4; ++j){
    float bv = blast[fg + 32*j];
    float uv = u[fg + 32*j];
    #pragma unroll
    for (int r = 0; r < 8; ++r){
      int gr = row0 + r0 + r;
      if (gr < N){
        size_t idx = (size_t)gr*128 + fg + 32*j;
        out0[idx] = acc[r][j] + bv + x[idx]*uv;
      }
    }
  }
}

extern "C" void kernel_launch(void* const* d_in, const int* in_sizes, int n_in,
                              void* d_out, int out_size, void* d_ws, size_t ws_size,
                              hipStream_t stream){
  const float* x     = (const float*)d_in[0];
  const void*  ei    = d_in[1];
  const float* ea    = (const float*)d_in[2];
  const float* Wsame = (const float*)d_in[3];
  const float* bsame = (const float*)d_in[4];
  const float* Wdiff = (const float*)d_in[5];
  const float* bdiff = (const float*)d_in[6];
  const float* WG    = (const float*)d_in[7];
  const float* rW1   = (const float*)d_in[8];
  const float* rb1   = (const float*)d_in[9];
  const float* rW2   = (const float*)d_in[10];
  const float* rb2   = (const float*)d_in[11];
  const float* Wlast = (const float*)d_in[12];
  const float* blast = (const float*)d_in[13];
  const float* u     = (const float*)d_in[14];

  const int N    = in_sizes[0] / 128;
  const int E    = in_sizes[1] / 2;
  const int NRES = in_sizes[8] / (128*128);

  float* out0  = (float*)d_out;
  float* msged = (float*)d_out + (size_t)N * 128;   // second output, built in place

  auto align256 = [](size_t v){ return (v + 255) & ~(size_t)255; };
  const size_t o_h     = 256;
  const size_t o_count = align256(o_h     + (size_t)N * 128 * 4);
  const size_t o_off   = align256(o_count + (size_t)N * 4);
  const size_t o_cur   = align256(o_off   + (size_t)(N + 1) * 4);
  const size_t o_perm  = align256(o_cur   + (size_t)N * 4);
  const size_t need    = o_perm + (size_t)E * 4;

  int*   flag = (int*)d_ws;
  float* h    = (float*)((char*)d_ws + o_h);
  int* count = (int*)((char*)d_ws + o_count);
  int* offs  = (int*)((char*)d_ws + o_off);
  int* cur   = (int*)((char*)d_ws + o_cur);
  int* perm  = (int*)((char*)d_ws + o_perm);
  (void)need; (void)ws_size;

  const int nb_node = (N + 63) / 64;

  detect_idx_kernel<<<1, 256, 0, stream>>>((const unsigned*)ei, flag);
  node_dual_kernel<<<nb_node, 256, 0, stream>>>(x, Wsame, bsame, Wdiff, bdiff, h, msged, N);

  zero_int_kernel<<<(N + 255) / 256, 256, 0, stream>>>(count, N);
  hist_kernel<<<1024, 256, 0, stream>>>(ei, flag, count, E);
  scan_kernel<<<1, 1024, 0, stream>>>(count, offs, cur, N);
  fill_kernel<<<1024, 256, 0, stream>>>(ei, flag, cur, perm, E);

  edge_reduce_kernel<<<2048, 256, 0, stream>>>(ea, ei, flag, WG, h, perm, offs,
                                               msged, N, E);

  tail_kernel<<<nb_node, 256, 0, stream>>>(msged, x, u, rW1, rb1, rW2, rb2, Wlast, blast,
                                           out0, N, NRES);
}

// Round 5
// 921.344 us; speedup vs baseline: 3.6891x; 1.5071x over previous
//
#include <hip/hip_runtime.h>
#include <hip/hip_bf16.h>

#define LN2F 0.69314718055994530942f

typedef short bf16x8 __attribute__((ext_vector_type(8)));
typedef float f32x4  __attribute__((ext_vector_type(4)));

__device__ __forceinline__ float ssp_f(float t){
  // softplus(t) - ln2, numerically stable
  return fmaxf(t, 0.0f) + __logf(1.0f + __expf(-fabsf(t))) - LN2F;
}
__device__ __forceinline__ unsigned short f2bf_u(float f){
  __hip_bfloat16 b = __float2bfloat16(f);
  return *reinterpret_cast<unsigned short*>(&b);
}

// ---------------- index width detection (int32 vs int64 edge_index) --------
__global__ void detect_idx_kernel(const unsigned* __restrict__ ei, int* __restrict__ flag){
  __shared__ int cnt;
  if (threadIdx.x == 0) cnt = 0;
  __syncthreads();
  int nz = 0;
  for (int i = threadIdx.x; i < 1024; i += 256)
    nz += (ei[2*i + 1] != 0u) ? 1 : 0;
  atomicAdd(&cnt, nz);
  __syncthreads();
  if (threadIdx.x == 0) *flag = (cnt > 64) ? 1 : 0;
}

__device__ __forceinline__ int load_idx(const void* ei, int is32, size_t pos){
  return is32 ? ((const int*)ei)[pos] : (int)(((const long long*)ei)[pos]);
}

// ---------------- CSR build ------------------------------------------------
__global__ void zero_int_kernel(int* __restrict__ p, int n){
  int i = blockIdx.x * 256 + threadIdx.x;
  if (i < n) p[i] = 0;
}

__global__ void hist_kernel(const void* __restrict__ ei, const int* __restrict__ flag,
                            int* __restrict__ count, int E){
  const int is32 = *flag;
  for (long long e = (long long)blockIdx.x * 256 + threadIdx.x; e < E;
       e += (long long)gridDim.x * 256){
    int d = load_idx(ei, is32, (size_t)((long long)E + e));
    atomicAdd(&count[d], 1);
  }
}

__global__ __launch_bounds__(1024) void scan_kernel(const int* __restrict__ count,
                                                    int* __restrict__ offs,
                                                    int* __restrict__ cur, int N){
  __shared__ int buf[1024];
  __shared__ int carry_s;
  if (threadIdx.x == 0) carry_s = 0;
  __syncthreads();
  for (int base = 0; base < N; base += 8192){
    int v[8];
    int i0 = base + threadIdx.x * 8;
    int s = 0;
    #pragma unroll
    for (int r = 0; r < 8; ++r){ int i = i0 + r; v[r] = (i < N) ? count[i] : 0; s += v[r]; }
    buf[threadIdx.x] = s;
    __syncthreads();
    #pragma unroll
    for (int off = 1; off < 1024; off <<= 1){
      int tv = (threadIdx.x >= off) ? buf[threadIdx.x - off] : 0;
      __syncthreads();
      buf[threadIdx.x] += tv;
      __syncthreads();
    }
    int run = buf[threadIdx.x] - s + carry_s;
    #pragma unroll
    for (int r = 0; r < 8; ++r){
      int i = i0 + r;
      if (i < N){ offs[i] = run; cur[i] = run; }
      run += v[r];
    }
    __syncthreads();
    if (threadIdx.x == 1023) carry_s += buf[1023];
    __syncthreads();
  }
  if (threadIdx.x == 0) offs[N] = carry_s;
}

__global__ void fill_kernel(const void* __restrict__ ei, const int* __restrict__ flag,
                            int* __restrict__ cur, int* __restrict__ perm, int E){
  const int is32 = *flag;
  for (long long e = (long long)blockIdx.x * 256 + threadIdx.x; e < E;
       e += (long long)gridDim.x * 256){
    int d = load_idx(ei, is32, (size_t)((long long)E + e));
    int slot = atomicAdd(&cur[d], 1);
    perm[slot] = (int)e;
  }
}

// ---------------- weight prep: fp32 row-major -> bf16 MFMA-fragment-linear --
// frag element q = ((ct*4+kt)*64 + lane)*8 + i  <->  W[ct*16+(lane&15)][kt*32+(lane>>4)*8+i]
struct WPtrs { const float* w[16]; };

__global__ __launch_bounds__(256) void prep_wfrag_kernel(WPtrs p, unsigned short* __restrict__ dst){
  const int m = blockIdx.x;
  const float* __restrict__ W = p.w[m];
  unsigned short* __restrict__ out = dst + (size_t)m * 16384;
  for (int q = threadIdx.x; q < 16384; q += 256){
    int i = q & 7, lane = (q >> 3) & 63, kt = (q >> 9) & 3, ct = q >> 11;
    int row = ct*16 + (lane & 15);
    int k   = kt*32 + (lane >> 4)*8 + i;
    out[q] = f2bf_u(W[row*128 + k]);
  }
}

// ---------------- MFMA GEMM core: 64x128 tile, K=128 ----------------------
// A_s: bf16 [64][136] row-major.  Bf: 16384 bf16 fragment-linear.
// wave wv owns rows wv*16..wv*16+15; acc[ct][q] = C[wv*16+(lane>>4)*4+q][ct*16+(lane&15)]
__device__ __forceinline__ void mfma_gemm128(const unsigned short (&A_s)[64][136],
                                             const unsigned short* Bf,
                                             int wv, int lane, f32x4 acc[8]){
  #pragma unroll
  for (int ct = 0; ct < 8; ++ct) acc[ct] = (f32x4){0.f, 0.f, 0.f, 0.f};
  const int r  = wv*16 + (lane & 15);
  const int kg = lane >> 4;
  #pragma unroll
  for (int kt = 0; kt < 4; ++kt){
    bf16x8 a = *(const bf16x8*)&A_s[r][kt*32 + kg*8];
    #pragma unroll
    for (int ct = 0; ct < 8; ++ct){
      bf16x8 b = *(const bf16x8*)&Bf[(size_t)((ct*4 + kt)*64 + lane)*8];
      acc[ct] = __builtin_amdgcn_mfma_f32_16x16x32_bf16(a, b, acc[ct], 0, 0, 0);
    }
  }
}

__device__ __forceinline__ void stage_bf(unsigned short* __restrict__ Bf,
                                         const unsigned short* __restrict__ src, int t){
  #pragma unroll
  for (int it = 0; it < 8; ++it){
    int off = (it*256 + t) * 8;
    *(uint4*)&Bf[off] = *(const uint4*)&src[off];
  }
}

// ---------------- kernel 1: h = ssp(xa W_diff^T + b), msged = ssp(xa W_same^T + b)
__global__ __launch_bounds__(256) void node_dual_kernel(
    const float* __restrict__ x, const unsigned short* __restrict__ wfrag,
    const float* __restrict__ bsame, const float* __restrict__ bdiff,
    float* __restrict__ h, float* __restrict__ msged, int N){
  __shared__ __align__(16) unsigned short A_s[64][136];
  __shared__ __align__(16) unsigned short Bf[16384];
  const int t = threadIdx.x, wv = t >> 6, lane = t & 63;
  const int kg = lane >> 4, c = lane & 15;
  const int row0 = blockIdx.x * 64;
  // stage A = bf16(ssp(x tile))
  for (int q = t; q < 1024; q += 256){
    int row = q >> 4, c0 = (q & 15) * 8;
    float4 va = make_float4(0.f,0.f,0.f,0.f), vb = va;
    if (row0 + row < N){
      va = *(const float4*)&x[(size_t)(row0 + row)*128 + c0];
      vb = *(const float4*)&x[(size_t)(row0 + row)*128 + c0 + 4];
    }
    uint4 w;
    w.x = f2bf_u(ssp_f(va.x)) | ((unsigned)f2bf_u(ssp_f(va.y)) << 16);
    w.y = f2bf_u(ssp_f(va.z)) | ((unsigned)f2bf_u(ssp_f(va.w)) << 16);
    w.z = f2bf_u(ssp_f(vb.x)) | ((unsigned)f2bf_u(ssp_f(vb.y)) << 16);
    w.w = f2bf_u(ssp_f(vb.z)) | ((unsigned)f2bf_u(ssp_f(vb.w)) << 16);
    *(uint4*)&A_s[row][c0] = w;
  }
  stage_bf(Bf, wfrag, t);               // W_same
  __syncthreads();
  f32x4 acc[8];
  mfma_gemm128(A_s, Bf, wv, lane, acc);
  #pragma unroll
  for (int ct = 0; ct < 8; ++ct){
    int col = ct*16 + c;
    float bv = bsame[col];
    #pragma unroll
    for (int q = 0; q < 4; ++q){
      int gr = row0 + wv*16 + kg*4 + q;
      if (gr < N) msged[(size_t)gr*128 + col] = ssp_f(acc[ct][q] + bv);
    }
  }
  __syncthreads();                      // all Bf reads done
  stage_bf(Bf, wfrag + 16384, t);       // W_diff
  __syncthreads();
  mfma_gemm128(A_s, Bf, wv, lane, acc);
  #pragma unroll
  for (int ct = 0; ct < 8; ++ct){
    int col = ct*16 + c;
    float bv = bdiff[col];
    #pragma unroll
    for (int q = 0; q < 4; ++q){
      int gr = row0 + wv*16 + kg*4 + q;
      if (gr < N) h[(size_t)gr*128 + col] = ssp_f(acc[ct][q] + bv);
    }
  }
}

// ---------------- fused edge phase: per (dst, feature-half) wave ----------
// msged[d][f] += sum_{p in [offs[d],offs[d+1])} (ea[perm[p]] . WG[f][:]) * h[src][f]
__global__ __launch_bounds__(256) void edge_reduce_kernel(
    const float* __restrict__ ea, const void* __restrict__ ei, const int* __restrict__ flag,
    const float* __restrict__ WG, const float* __restrict__ h,
    const int* __restrict__ perm, const int* __restrict__ offs,
    float* __restrict__ msged, int N, int E){
  const int is32 = *flag;
  const int wave  = blockIdx.x * 4 + (threadIdx.x >> 6);
  const int lane  = threadIdx.x & 63;
  const int half  = wave & 1;
  const int f     = half * 64 + lane;
  const int nhw   = (gridDim.x * 4) >> 1;

  float wreg[64];
  #pragma unroll
  for (int k4 = 0; k4 < 16; ++k4){
    float4 v = *(const float4*)&WG[(size_t)f*64 + k4*4];
    wreg[k4*4+0]=v.x; wreg[k4*4+1]=v.y; wreg[k4*4+2]=v.z; wreg[k4*4+3]=v.w;
  }

  for (int d = wave >> 1; d < N; d += nhw){
    const int beg = offs[d], end = offs[d+1];
    float acc = 0.f;
    int p = beg;
    for (; p + 2 <= end; p += 2){
      int e0 = __builtin_amdgcn_readfirstlane(perm[p]);
      int e1 = __builtin_amdgcn_readfirstlane(perm[p+1]);
      int s0 = __builtin_amdgcn_readfirstlane(load_idx(ei, is32, (size_t)e0));
      int s1 = __builtin_amdgcn_readfirstlane(load_idx(ei, is32, (size_t)e1));
      float h0 = h[(size_t)s0*128 + f];          // hoisted, independent vector loads
      float h1 = h[(size_t)s1*128 + f];
      const float* __restrict__ r0 = &ea[(size_t)e0*64];
      const float* __restrict__ r1 = &ea[(size_t)e1*64];
      float g0 = 0.f, g1 = 0.f;
      #pragma unroll
      for (int k = 0; k < 64; ++k){
        g0 = __builtin_fmaf(r0[k], wreg[k], g0);
        g1 = __builtin_fmaf(r1[k], wreg[k], g1);
      }
      acc = __builtin_fmaf(g0, h0, acc);
      acc = __builtin_fmaf(g1, h1, acc);
    }
    if (p < end){
      int e0 = __builtin_amdgcn_readfirstlane(perm[p]);
      int s0 = __builtin_amdgcn_readfirstlane(load_idx(ei, is32, (size_t)e0));
      float h0 = h[(size_t)s0*128 + f];
      const float* __restrict__ r0 = &ea[(size_t)e0*64];
      float g0 = 0.f;
      #pragma unroll
      for (int k = 0; k < 64; ++k) g0 = __builtin_fmaf(r0[k], wreg[k], g0);
      acc = __builtin_fmaf(g0, h0, acc);
    }
    msged[(size_t)d*128 + f] += acc;             // owner-exclusive, non-atomic
  }
}

// ---------------- kernel 3: fused residual chain + final linear + skip ----
__global__ __launch_bounds__(256) void tail_kernel(
    const float* __restrict__ msged, const float* __restrict__ x, const float* __restrict__ u,
    const unsigned short* __restrict__ wfrag,
    const float* __restrict__ rb1, const float* __restrict__ rb2,
    const float* __restrict__ blast, float* __restrict__ out0, int N, int NRES){
  __shared__ __align__(16) unsigned short A_s[64][136];
  __shared__ __align__(16) unsigned short Bf[16384];
  const int t = threadIdx.x, wv = t >> 6, lane = t & 63;
  const int kg = lane >> 4, c = lane & 15;
  const int row0 = blockIdx.x * 64;

  float treg[8][4];
  #pragma unroll
  for (int ct = 0; ct < 8; ++ct)
    #pragma unroll
    for (int q = 0; q < 4; ++q){
      int gr = row0 + wv*16 + kg*4 + q;
      treg[ct][q] = (gr < N) ? msged[(size_t)gr*128 + ct*16 + c] : 0.f;
    }

  f32x4 acc[8];
  for (int l = 0; l < NRES; ++l){
    __syncthreads();                    // previous Bf readers done
    #pragma unroll
    for (int ct = 0; ct < 8; ++ct)
      #pragma unroll
      for (int q = 0; q < 4; ++q)
        A_s[wv*16 + kg*4 + q][ct*16 + c] = f2bf_u(ssp_f(treg[ct][q]));
    stage_bf(Bf, wfrag + (size_t)(2 + 2*l)*16384, t);
    __syncthreads();
    mfma_gemm128(A_s, Bf, wv, lane, acc);
    __syncthreads();                    // A_s/Bf reads done before overwrite
    #pragma unroll
    for (int ct = 0; ct < 8; ++ct){
      float bv = rb1[l*128 + ct*16 + c];
      #pragma unroll
      for (int q = 0; q < 4; ++q)
        A_s[wv*16 + kg*4 + q][ct*16 + c] = f2bf_u(ssp_f(acc[ct][q] + bv));
    }
    stage_bf(Bf, wfrag + (size_t)(3 + 2*l)*16384, t);
    __syncthreads();
    mfma_gemm128(A_s, Bf, wv, lane, acc);
    #pragma unroll
    for (int ct = 0; ct < 8; ++ct){
      float bv = rb2[l*128 + ct*16 + c];
      #pragma unroll
      for (int q = 0; q < 4; ++q) treg[ct][q] += acc[ct][q] + bv;
    }
  }
  __syncthreads();
  #pragma unroll
  for (int ct = 0; ct < 8; ++ct)
    #pragma unroll
    for (int q = 0; q < 4; ++q)
      A_s[wv*16 + kg*4 + q][ct*16 + c] = f2bf_u(ssp_f(treg[ct][q]));
  stage_bf(Bf, wfrag + (size_t)(2 + 2*NRES)*16384, t);
  __syncthreads();
  mfma_gemm128(A_s, Bf, wv, lane, acc);
  #pragma unroll
  for (int ct = 0; ct < 8; ++ct){
    int col = ct*16 + c;
    float bv = blast[col];
    float uv = u[col];
    #pragma unroll
    for (int q = 0; q < 4; ++q){
      int gr = row0 + wv*16 + kg*4 + q;
      if (gr < N){
        size_t idx = (size_t)gr*128 + col;
        out0[idx] = acc[ct][q] + bv + x[idx]*uv;
      }
    }
  }
}

extern "C" void kernel_launch(void* const* d_in, const int* in_sizes, int n_in,
                              void* d_out, int out_size, void* d_ws, size_t ws_size,
                              hipStream_t stream){
  const float* x     = (const float*)d_in[0];
  const void*  ei    = d_in[1];
  const float* ea    = (const float*)d_in[2];
  const float* Wsame = (const float*)d_in[3];
  const float* bsame = (const float*)d_in[4];
  const float* Wdiff = (const float*)d_in[5];
  const float* bdiff = (const float*)d_in[6];
  const float* WG    = (const float*)d_in[7];
  const float* rW1   = (const float*)d_in[8];
  const float* rb1   = (const float*)d_in[9];
  const float* rW2   = (const float*)d_in[10];
  const float* rb2   = (const float*)d_in[11];
  const float* Wlast = (const float*)d_in[12];
  const float* blast = (const float*)d_in[13];
  const float* u     = (const float*)d_in[14];

  const int N    = in_sizes[0] / 128;
  const int E    = in_sizes[1] / 2;
  int NRES = in_sizes[8] / (128*128);
  if (NRES > 6) NRES = 6;               // WPtrs capacity guard

  float* out0  = (float*)d_out;
  float* msged = (float*)d_out + (size_t)N * 128;   // second output, built in place

  auto align256 = [](size_t v){ return (v + 255) & ~(size_t)255; };
  const size_t o_h     = 256;
  const size_t o_count = align256(o_h     + (size_t)N * 128 * 4);
  const size_t o_off   = align256(o_count + (size_t)N * 4);
  const size_t o_cur   = align256(o_off   + (size_t)(N + 1) * 4);
  const size_t o_perm  = align256(o_cur   + (size_t)N * 4);
  const size_t o_wfrag = align256(o_perm  + (size_t)E * 4);

  int*   flag = (int*)d_ws;
  float* h    = (float*)((char*)d_ws + o_h);
  int* count  = (int*)((char*)d_ws + o_count);
  int* offs   = (int*)((char*)d_ws + o_off);
  int* cur    = (int*)((char*)d_ws + o_cur);
  int* perm   = (int*)((char*)d_ws + o_perm);
  unsigned short* wfrag = (unsigned short*)((char*)d_ws + o_wfrag);
  (void)ws_size;

  const int nw = 3 + 2*NRES;            // same, diff, (W1,W2)*NRES, last
  WPtrs wp;
  wp.w[0] = Wsame;
  wp.w[1] = Wdiff;
  for (int l = 0; l < NRES; ++l){
    wp.w[2 + 2*l] = rW1 + (size_t)l*16384;
    wp.w[3 + 2*l] = rW2 + (size_t)l*16384;
  }
  wp.w[2 + 2*NRES] = Wlast;
  for (int i = nw; i < 16; ++i) wp.w[i] = Wlast;

  const int nb_node = (N + 63) / 64;

  detect_idx_kernel<<<1, 256, 0, stream>>>((const unsigned*)ei, flag);
  prep_wfrag_kernel<<<nw, 256, 0, stream>>>(wp, wfrag);
  node_dual_kernel<<<nb_node, 256, 0, stream>>>(x, wfrag, bsame, bdiff, h, msged, N);

  zero_int_kernel<<<(N + 255) / 256, 256, 0, stream>>>(count, N);
  hist_kernel<<<1024, 256, 0, stream>>>(ei, flag, count, E);
  scan_kernel<<<1, 1024, 0, stream>>>(count, offs, cur, N);
  fill_kernel<<<1024, 256, 0, stream>>>(ei, flag, cur, perm, E);

  edge_reduce_kernel<<<2048, 256, 0, stream>>>(ea, ei, flag, WG, h, perm, offs,
                                               msged, N, E);

  tail_kernel<<<nb_node, 256, 0, stream>>>(msged, x, u, wfrag, rb1, rb2, blast,
                                           out0, N, NRES);
}

// Round 6
// 477.421 us; speedup vs baseline: 7.1194x; 1.9298x over previous
//
#include <hip/hip_runtime.h>
#include <hip/hip_bf16.h>

#define LN2F 0.69314718055994530942f

typedef short bf16x8 __attribute__((ext_vector_type(8)));
typedef float f32x4  __attribute__((ext_vector_type(4)));

__device__ __forceinline__ float ssp_f(float t){
  // softplus(t) - ln2, numerically stable
  return fmaxf(t, 0.0f) + __logf(1.0f + __expf(-fabsf(t))) - LN2F;
}
__device__ __forceinline__ unsigned short f2bf_u(float f){
  __hip_bfloat16 b = __float2bfloat16(f);
  return *reinterpret_cast<unsigned short*>(&b);
}

// ---------------- index width detection (int32 vs int64 edge_index) --------
__global__ void detect_idx_kernel(const unsigned* __restrict__ ei, int* __restrict__ flag){
  __shared__ int cnt;
  if (threadIdx.x == 0) cnt = 0;
  __syncthreads();
  int nz = 0;
  for (int i = threadIdx.x; i < 1024; i += 256)
    nz += (ei[2*i + 1] != 0u) ? 1 : 0;
  atomicAdd(&cnt, nz);
  __syncthreads();
  if (threadIdx.x == 0) *flag = (cnt > 64) ? 1 : 0;
}

__device__ __forceinline__ int load_idx(const void* ei, int is32, size_t pos){
  return is32 ? ((const int*)ei)[pos] : (int)(((const long long*)ei)[pos]);
}

// ---------------- CSR build ------------------------------------------------
__global__ void zero_int_kernel(int* __restrict__ p, int n){
  int i = blockIdx.x * 256 + threadIdx.x;
  if (i < n) p[i] = 0;
}

__global__ void hist_kernel(const void* __restrict__ ei, const int* __restrict__ flag,
                            int* __restrict__ count, int E){
  const int is32 = *flag;
  for (long long e = (long long)blockIdx.x * 256 + threadIdx.x; e < E;
       e += (long long)gridDim.x * 256){
    int d = load_idx(ei, is32, (size_t)((long long)E + e));
    atomicAdd(&count[d], 1);
  }
}

__global__ __launch_bounds__(1024) void scan_kernel(const int* __restrict__ count,
                                                    int* __restrict__ offs,
                                                    int* __restrict__ cur, int N){
  __shared__ int buf[1024];
  __shared__ int carry_s;
  if (threadIdx.x == 0) carry_s = 0;
  __syncthreads();
  for (int base = 0; base < N; base += 8192){
    int v[8];
    int i0 = base + threadIdx.x * 8;
    int s = 0;
    #pragma unroll
    for (int r = 0; r < 8; ++r){ int i = i0 + r; v[r] = (i < N) ? count[i] : 0; s += v[r]; }
    buf[threadIdx.x] = s;
    __syncthreads();
    #pragma unroll
    for (int off = 1; off < 1024; off <<= 1){
      int tv = (threadIdx.x >= off) ? buf[threadIdx.x - off] : 0;
      __syncthreads();
      buf[threadIdx.x] += tv;
      __syncthreads();
    }
    int run = buf[threadIdx.x] - s + carry_s;
    #pragma unroll
    for (int r = 0; r < 8; ++r){
      int i = i0 + r;
      if (i < N){ offs[i] = run; cur[i] = run; }
      run += v[r];
    }
    __syncthreads();
    if (threadIdx.x == 1023) carry_s += buf[1023];
    __syncthreads();
  }
  if (threadIdx.x == 0) offs[N] = carry_s;
}

// se[slot] = (e, src, dst, 0), slots sorted by dst (CSR order)
__global__ void fill_kernel(const void* __restrict__ ei, const int* __restrict__ flag,
                            int* __restrict__ cur, int4* __restrict__ se, int E){
  const int is32 = *flag;
  for (long long e = (long long)blockIdx.x * 256 + threadIdx.x; e < E;
       e += (long long)gridDim.x * 256){
    int s = load_idx(ei, is32, (size_t)e);
    int d = load_idx(ei, is32, (size_t)((long long)E + e));
    int slot = atomicAdd(&cur[d], 1);
    se[slot] = make_int4((int)e, s, d, 0);
  }
}

// ---------------- weight prep: fp32 row-major -> bf16 MFMA-fragment-linear --
// frag element q = ((ct*4+kt)*64 + lane)*8 + i  <->  W[ct*16+(lane&15)][kt*32+(lane>>4)*8+i]
struct WPtrs { const float* w[16]; };

__global__ __launch_bounds__(256) void prep_wfrag_kernel(WPtrs p, unsigned short* __restrict__ dst){
  const int m = blockIdx.x;
  const float* __restrict__ W = p.w[m];
  unsigned short* __restrict__ out = dst + (size_t)m * 16384;
  for (int q = threadIdx.x; q < 16384; q += 256){
    int i = q & 7, lane = (q >> 3) & 63, kt = (q >> 9) & 3, ct = q >> 11;
    int row = ct*16 + (lane & 15);
    int k   = kt*32 + (lane >> 4)*8 + i;
    out[q] = f2bf_u(W[row*128 + k]);
  }
}

// WG [128 f][64 k] -> bf16 fragments for the edge gate GEMM
// q = ((((half*4+nt)*2+kt)*64)+lane)*8+i <-> WG[half*64+nt*16+(lane&15)][kt*32+(lane>>4)*8+i]
__global__ __launch_bounds__(256) void prep_wgfrag_kernel(const float* __restrict__ WG,
                                                          unsigned short* __restrict__ dst){
  for (int q = blockIdx.x*256 + threadIdx.x; q < 8192; q += gridDim.x*256){
    int i = q & 7, lane = (q >> 3) & 63, kt = (q >> 9) & 1, nt = (q >> 10) & 3, half = q >> 12;
    int f = half*64 + nt*16 + (lane & 15);
    int k = kt*32 + (lane >> 4)*8 + i;
    dst[q] = f2bf_u(WG[(size_t)f*64 + k]);
  }
}

// ---------------- MFMA GEMM core: 64x128 tile, K=128 ----------------------
__device__ __forceinline__ void mfma_gemm128(const unsigned short (&A_s)[64][136],
                                             const unsigned short* Bf,
                                             int wv, int lane, f32x4 acc[8]){
  #pragma unroll
  for (int ct = 0; ct < 8; ++ct) acc[ct] = (f32x4){0.f, 0.f, 0.f, 0.f};
  const int r  = wv*16 + (lane & 15);
  const int kg = lane >> 4;
  #pragma unroll
  for (int kt = 0; kt < 4; ++kt){
    bf16x8 a = *(const bf16x8*)&A_s[r][kt*32 + kg*8];
    #pragma unroll
    for (int ct = 0; ct < 8; ++ct){
      bf16x8 b = *(const bf16x8*)&Bf[(size_t)((ct*4 + kt)*64 + lane)*8];
      acc[ct] = __builtin_amdgcn_mfma_f32_16x16x32_bf16(a, b, acc[ct], 0, 0, 0);
    }
  }
}

__device__ __forceinline__ void stage_bf(unsigned short* __restrict__ Bf,
                                         const unsigned short* __restrict__ src, int t){
  #pragma unroll
  for (int it = 0; it < 8; ++it){
    int off = (it*256 + t) * 8;
    *(uint4*)&Bf[off] = *(const uint4*)&src[off];
  }
}

// ---------------- kernel 1: h = ssp(xa W_diff^T + b), msged = ssp(xa W_same^T + b)
__global__ __launch_bounds__(256) void node_dual_kernel(
    const float* __restrict__ x, const unsigned short* __restrict__ wfrag,
    const float* __restrict__ bsame, const float* __restrict__ bdiff,
    float* __restrict__ h, float* __restrict__ msged, int N){
  __shared__ __align__(16) unsigned short A_s[64][136];
  __shared__ __align__(16) unsigned short Bf[16384];
  const int t = threadIdx.x, wv = t >> 6, lane = t & 63;
  const int kg = lane >> 4, c = lane & 15;
  const int row0 = blockIdx.x * 64;
  for (int q = t; q < 1024; q += 256){
    int row = q >> 4, c0 = (q & 15) * 8;
    float4 va = make_float4(0.f,0.f,0.f,0.f), vb = va;
    if (row0 + row < N){
      va = *(const float4*)&x[(size_t)(row0 + row)*128 + c0];
      vb = *(const float4*)&x[(size_t)(row0 + row)*128 + c0 + 4];
    }
    uint4 w;
    w.x = f2bf_u(ssp_f(va.x)) | ((unsigned)f2bf_u(ssp_f(va.y)) << 16);
    w.y = f2bf_u(ssp_f(va.z)) | ((unsigned)f2bf_u(ssp_f(va.w)) << 16);
    w.z = f2bf_u(ssp_f(vb.x)) | ((unsigned)f2bf_u(ssp_f(vb.y)) << 16);
    w.w = f2bf_u(ssp_f(vb.z)) | ((unsigned)f2bf_u(ssp_f(vb.w)) << 16);
    *(uint4*)&A_s[row][c0] = w;
  }
  stage_bf(Bf, wfrag, t);               // W_same
  __syncthreads();
  f32x4 acc[8];
  mfma_gemm128(A_s, Bf, wv, lane, acc);
  #pragma unroll
  for (int ct = 0; ct < 8; ++ct){
    int col = ct*16 + c;
    float bv = bsame[col];
    #pragma unroll
    for (int q = 0; q < 4; ++q){
      int gr = row0 + wv*16 + kg*4 + q;
      if (gr < N) msged[(size_t)gr*128 + col] = ssp_f(acc[ct][q] + bv);
    }
  }
  __syncthreads();
  stage_bf(Bf, wfrag + 16384, t);       // W_diff
  __syncthreads();
  mfma_gemm128(A_s, Bf, wv, lane, acc);
  #pragma unroll
  for (int ct = 0; ct < 8; ++ct){
    int col = ct*16 + c;
    float bv = bdiff[col];
    #pragma unroll
    for (int q = 0; q < 4; ++q){
      int gr = row0 + wv*16 + kg*4 + q;
      if (gr < N) h[(size_t)gr*128 + col] = ssp_f(acc[ct][q] + bv);
    }
  }
}

// ---------------- edge phase: batched MFMA gate + segmented reduce --------
// Each wave owns a dst-aligned contiguous slot range (one feature half).
// Per 16-slot batch: gate = ea_rows @ WG^T (MFMA), P = gate*h[src] -> LDS,
// then segmented sum over dst runs (boundaries via ballot mask).
__global__ __launch_bounds__(256) void edge_mfma_kernel(
    const float* __restrict__ ea, const unsigned short* __restrict__ wgfrag,
    const float* __restrict__ h, const int4* __restrict__ se,
    const int* __restrict__ offs, float* __restrict__ msged, int N, int E, int KW){
  __shared__ float P_s[4][16][66];
  const int t = threadIdx.x, wv = t >> 6, lane = t & 63;
  const int kg = lane >> 4, c = lane & 15;
  const int gw = blockIdx.x * 4 + wv;
  const int half = gw & 1;
  const int widx = gw >> 1;
  if (widx >= KW) return;
  // balanced dst-aligned slot range via binary search on offs
  long long tt0 = (long long)widx * E / KW;
  long long tt1 = (long long)(widx + 1) * E / KW;
  int lo = 0, hi = N;
  while (lo < hi){ int mid = (lo + hi) >> 1; if ((long long)offs[mid] < tt0) lo = mid + 1; else hi = mid; }
  const int d_lo = lo;
  hi = N;
  while (lo < hi){ int mid = (lo + hi) >> 1; if ((long long)offs[mid] < tt1) lo = mid + 1; else hi = mid; }
  const int d_hi = lo;
  if (d_lo >= d_hi) return;
  const int s_beg = offs[d_lo], s_end = offs[d_hi];
  if (s_beg >= s_end) return;

  // preload this half's WG fragments into registers (reused for all batches)
  bf16x8 bw[4][2];
  #pragma unroll
  for (int nt = 0; nt < 4; ++nt)
    #pragma unroll
    for (int kt = 0; kt < 2; ++kt)
      bw[nt][kt] = *(const bf16x8*)&wgfrag[(size_t)((((half*4+nt)*2+kt)*64)+lane)*8];

  float sum_v = 0.f;
  for (int p = s_beg; p < s_end; p += 16){
    const int nb = min(16, s_end - p);
    int4 s4 = se[p + min(c, nb-1)];                  // slot c metadata (e, src, dst)
    int dnext = -1;
    if (nb == 16 && p + 16 < s_end) dnext = ((const int*)se)[(size_t)(p+16)*4 + 2];
    int dn = __shfl(s4.z, (c + 1) & 15, 16);
    if (c == nb - 1) dn = dnext;
    int flg = (c < nb) && (dn != s4.z);
    unsigned msk = (unsigned)(__ballot(flg != 0) & 0xFFFFull);

    // A fragments straight from global: row = slot c, k = kt*32 + kg*8 + i
    const float* ra = &ea[(size_t)s4.x * 64];
    float4 a00 = *(const float4*)&ra[kg*8];
    float4 a01 = *(const float4*)&ra[kg*8 + 4];
    float4 a10 = *(const float4*)&ra[32 + kg*8];
    float4 a11 = *(const float4*)&ra[32 + kg*8 + 4];

    // h values for acc elements (nt, q): row = src of slot kg*4+q
    int sv[4];
    #pragma unroll
    for (int q = 0; q < 4; ++q) sv[q] = __shfl(s4.y, kg*4 + q, 16);
    float hv[4][4];
    #pragma unroll
    for (int q = 0; q < 4; ++q){
      const float* hr = &h[(size_t)sv[q]*128 + half*64 + c];
      #pragma unroll
      for (int nt = 0; nt < 4; ++nt) hv[nt][q] = hr[nt*16];
    }

    bf16x8 af0, af1;
    unsigned short* w0 = (unsigned short*)&af0;
    unsigned short* w1 = (unsigned short*)&af1;
    w0[0]=f2bf_u(a00.x); w0[1]=f2bf_u(a00.y); w0[2]=f2bf_u(a00.z); w0[3]=f2bf_u(a00.w);
    w0[4]=f2bf_u(a01.x); w0[5]=f2bf_u(a01.y); w0[6]=f2bf_u(a01.z); w0[7]=f2bf_u(a01.w);
    w1[0]=f2bf_u(a10.x); w1[1]=f2bf_u(a10.y); w1[2]=f2bf_u(a10.z); w1[3]=f2bf_u(a10.w);
    w1[4]=f2bf_u(a11.x); w1[5]=f2bf_u(a11.y); w1[6]=f2bf_u(a11.z); w1[7]=f2bf_u(a11.w);

    f32x4 acc[4];
    #pragma unroll
    for (int nt = 0; nt < 4; ++nt) acc[nt] = (f32x4){0.f,0.f,0.f,0.f};
    #pragma unroll
    for (int nt = 0; nt < 4; ++nt){
      acc[nt] = __builtin_amdgcn_mfma_f32_16x16x32_bf16(af0, bw[nt][0], acc[nt], 0, 0, 0);
      acc[nt] = __builtin_amdgcn_mfma_f32_16x16x32_bf16(af1, bw[nt][1], acc[nt], 0, 0, 0);
    }

    // P = gate * h -> LDS [slot][f']  (f' = nt*16+c in 0..63)
    #pragma unroll
    for (int nt = 0; nt < 4; ++nt)
      #pragma unroll
      for (int q = 0; q < 4; ++q)
        P_s[wv][kg*4 + q][nt*16 + c] = acc[nt][q] * hv[nt][q];

    __builtin_amdgcn_s_waitcnt(0);   // lgkmcnt(0): P_s writes visible to own wave

    // segmented reduce over dst runs (uniform branches via mask)
    for (int i = 0; i < nb; ++i){
      sum_v += P_s[wv][i][lane];
      if (msk & (1u << i)){
        int dd = __builtin_amdgcn_readlane(s4.z, i);
        float* mp = &msged[(size_t)dd*128 + half*64 + lane];
        *mp += sum_v;                  // owner-exclusive, non-atomic
        sum_v = 0.f;
      }
    }
  }
}

// ---------------- kernel 3: fused residual chain + final linear + skip ----
__global__ __launch_bounds__(256) void tail_kernel(
    const float* __restrict__ msged, const float* __restrict__ x, const float* __restrict__ u,
    const unsigned short* __restrict__ wfrag,
    const float* __restrict__ rb1, const float* __restrict__ rb2,
    const float* __restrict__ blast, float* __restrict__ out0, int N, int NRES){
  __shared__ __align__(16) unsigned short A_s[64][136];
  __shared__ __align__(16) unsigned short Bf[16384];
  const int t = threadIdx.x, wv = t >> 6, lane = t & 63;
  const int kg = lane >> 4, c = lane & 15;
  const int row0 = blockIdx.x * 64;

  float treg[8][4];
  #pragma unroll
  for (int ct = 0; ct < 8; ++ct)
    #pragma unroll
    for (int q = 0; q < 4; ++q){
      int gr = row0 + wv*16 + kg*4 + q;
      treg[ct][q] = (gr < N) ? msged[(size_t)gr*128 + ct*16 + c] : 0.f;
    }

  f32x4 acc[8];
  for (int l = 0; l < NRES; ++l){
    __syncthreads();
    #pragma unroll
    for (int ct = 0; ct < 8; ++ct)
      #pragma unroll
      for (int q = 0; q < 4; ++q)
        A_s[wv*16 + kg*4 + q][ct*16 + c] = f2bf_u(ssp_f(treg[ct][q]));
    stage_bf(Bf, wfrag + (size_t)(2 + 2*l)*16384, t);
    __syncthreads();
    mfma_gemm128(A_s, Bf, wv, lane, acc);
    __syncthreads();
    #pragma unroll
    for (int ct = 0; ct < 8; ++ct){
      float bv = rb1[l*128 + ct*16 + c];
      #pragma unroll
      for (int q = 0; q < 4; ++q)
        A_s[wv*16 + kg*4 + q][ct*16 + c] = f2bf_u(ssp_f(acc[ct][q] + bv));
    }
    stage_bf(Bf, wfrag + (size_t)(3 + 2*l)*16384, t);
    __syncthreads();
    mfma_gemm128(A_s, Bf, wv, lane, acc);
    #pragma unroll
    for (int ct = 0; ct < 8; ++ct){
      float bv = rb2[l*128 + ct*16 + c];
      #pragma unroll
      for (int q = 0; q < 4; ++q) treg[ct][q] += acc[ct][q] + bv;
    }
  }
  __syncthreads();
  #pragma unroll
  for (int ct = 0; ct < 8; ++ct)
    #pragma unroll
    for (int q = 0; q < 4; ++q)
      A_s[wv*16 + kg*4 + q][ct*16 + c] = f2bf_u(ssp_f(treg[ct][q]));
  stage_bf(Bf, wfrag + (size_t)(2 + 2*NRES)*16384, t);
  __syncthreads();
  mfma_gemm128(A_s, Bf, wv, lane, acc);
  #pragma unroll
  for (int ct = 0; ct < 8; ++ct){
    int col = ct*16 + c;
    float bv = blast[col];
    float uv = u[col];
    #pragma unroll
    for (int q = 0; q < 4; ++q){
      int gr = row0 + wv*16 + kg*4 + q;
      if (gr < N){
        size_t idx = (size_t)gr*128 + col;
        out0[idx] = acc[ct][q] + bv + x[idx]*uv;
      }
    }
  }
}

extern "C" void kernel_launch(void* const* d_in, const int* in_sizes, int n_in,
                              void* d_out, int out_size, void* d_ws, size_t ws_size,
                              hipStream_t stream){
  const float* x     = (const float*)d_in[0];
  const void*  ei    = d_in[1];
  const float* ea    = (const float*)d_in[2];
  const float* Wsame = (const float*)d_in[3];
  const float* bsame = (const float*)d_in[4];
  const float* Wdiff = (const float*)d_in[5];
  const float* bdiff = (const float*)d_in[6];
  const float* WG    = (const float*)d_in[7];
  const float* rW1   = (const float*)d_in[8];
  const float* rb1   = (const float*)d_in[9];
  const float* rW2   = (const float*)d_in[10];
  const float* rb2   = (const float*)d_in[11];
  const float* Wlast = (const float*)d_in[12];
  const float* blast = (const float*)d_in[13];
  const float* u     = (const float*)d_in[14];

  const int N    = in_sizes[0] / 128;
  const int E    = in_sizes[1] / 2;
  int NRES = in_sizes[8] / (128*128);
  if (NRES > 6) NRES = 6;               // WPtrs capacity guard

  float* out0  = (float*)d_out;
  float* msged = (float*)d_out + (size_t)N * 128;   // second output, built in place

  auto align256 = [](size_t v){ return (v + 255) & ~(size_t)255; };
  const size_t o_h      = 256;
  const size_t o_count  = align256(o_h      + (size_t)N * 128 * 4);
  const size_t o_off    = align256(o_count  + (size_t)N * 4);
  const size_t o_cur    = align256(o_off    + (size_t)(N + 1) * 4);
  const size_t o_se     = align256(o_cur    + (size_t)N * 4);
  const size_t o_wfrag  = align256(o_se     + (size_t)E * 16);
  const size_t o_wgfrag = align256(o_wfrag  + (size_t)16 * 16384 * 2);

  int*   flag = (int*)d_ws;
  float* h    = (float*)((char*)d_ws + o_h);
  int* count  = (int*)((char*)d_ws + o_count);
  int* offs   = (int*)((char*)d_ws + o_off);
  int* cur    = (int*)((char*)d_ws + o_cur);
  int4* se    = (int4*)((char*)d_ws + o_se);
  unsigned short* wfrag  = (unsigned short*)((char*)d_ws + o_wfrag);
  unsigned short* wgfrag = (unsigned short*)((char*)d_ws + o_wgfrag);
  (void)ws_size;

  const int nw = 3 + 2*NRES;            // same, diff, (W1,W2)*NRES, last
  WPtrs wp;
  wp.w[0] = Wsame;
  wp.w[1] = Wdiff;
  for (int l = 0; l < NRES; ++l){
    wp.w[2 + 2*l] = rW1 + (size_t)l*16384;
    wp.w[3 + 2*l] = rW2 + (size_t)l*16384;
  }
  wp.w[2 + 2*NRES] = Wlast;
  for (int i = nw; i < 16; ++i) wp.w[i] = Wlast;

  const int nb_node = (N + 63) / 64;
  const int nb_edge = 2048;
  const int KW = nb_edge * 4 / 2;       // waves per feature-half

  detect_idx_kernel<<<1, 256, 0, stream>>>((const unsigned*)ei, flag);
  prep_wfrag_kernel<<<nw, 256, 0, stream>>>(wp, wfrag);
  prep_wgfrag_kernel<<<32, 256, 0, stream>>>(WG, wgfrag);
  node_dual_kernel<<<nb_node, 256, 0, stream>>>(x, wfrag, bsame, bdiff, h, msged, N);

  zero_int_kernel<<<(N + 255) / 256, 256, 0, stream>>>(count, N);
  hist_kernel<<<1024, 256, 0, stream>>>(ei, flag, count, E);
  scan_kernel<<<1, 1024, 0, stream>>>(count, offs, cur, N);
  fill_kernel<<<1024, 256, 0, stream>>>(ei, flag, cur, se, E);

  edge_mfma_kernel<<<nb_edge, 256, 0, stream>>>(ea, wgfrag, h, se, offs, msged, N, E, KW);

  tail_kernel<<<nb_node, 256, 0, stream>>>(msged, x, u, wfrag, rb1, rb2, blast,
                                           out0, N, NRES);
}

// Round 7
// 369.065 us; speedup vs baseline: 9.2096x; 1.2936x over previous
//
#include <hip/hip_runtime.h>
#include <hip/hip_bf16.h>

#define LN2F 0.69314718055994530942f

typedef short bf16x8 __attribute__((ext_vector_type(8)));
typedef float f32x4  __attribute__((ext_vector_type(4)));

__device__ __forceinline__ float ssp_f(float t){
  // softplus(t) - ln2, numerically stable
  return fmaxf(t, 0.0f) + __logf(1.0f + __expf(-fabsf(t))) - LN2F;
}
__device__ __forceinline__ unsigned short f2bf_u(float f){
  __hip_bfloat16 b = __float2bfloat16(f);
  return *reinterpret_cast<unsigned short*>(&b);
}
__device__ __forceinline__ float bf2f(unsigned short u){
  __hip_bfloat16 b = *reinterpret_cast<__hip_bfloat16*>(&u);
  return __bfloat162float(b);
}

// ---------------- index width detection (int32 vs int64 edge_index) --------
__global__ void detect_idx_kernel(const unsigned* __restrict__ ei, int* __restrict__ flag){
  __shared__ int cnt;
  if (threadIdx.x == 0) cnt = 0;
  __syncthreads();
  int nz = 0;
  for (int i = threadIdx.x; i < 1024; i += 256)
    nz += (ei[2*i + 1] != 0u) ? 1 : 0;
  atomicAdd(&cnt, nz);
  __syncthreads();
  if (threadIdx.x == 0) *flag = (cnt > 64) ? 1 : 0;
}

__device__ __forceinline__ int load_idx(const void* ei, int is32, size_t pos){
  return is32 ? ((const int*)ei)[pos] : (int)(((const long long*)ei)[pos]);
}

// ---------------- CSR build ------------------------------------------------
__global__ void zero_int_kernel(int* __restrict__ p, int n){
  int i = blockIdx.x * 256 + threadIdx.x;
  if (i < n) p[i] = 0;
}

__global__ void hist_kernel(const void* __restrict__ ei, const int* __restrict__ flag,
                            int* __restrict__ count, int E){
  const int is32 = *flag;
  for (long long e = (long long)blockIdx.x * 256 + threadIdx.x; e < E;
       e += (long long)gridDim.x * 256){
    int d = load_idx(ei, is32, (size_t)((long long)E + e));
    atomicAdd(&count[d], 1);
  }
}

// three-pass scan: block sums -> serial scan of block sums -> local scan
__global__ __launch_bounds__(256) void scan1_kernel(const int* __restrict__ count,
                                                    int* __restrict__ bsum, int N){
  __shared__ int red[256];
  const int t = threadIdx.x;
  int i0 = blockIdx.x * 2048 + t * 8;
  int s = 0;
  #pragma unroll
  for (int r = 0; r < 8; ++r){ int i = i0 + r; s += (i < N) ? count[i] : 0; }
  red[t] = s;
  __syncthreads();
  for (int off = 128; off > 0; off >>= 1){
    if (t < off) red[t] += red[t + off];
    __syncthreads();
  }
  if (t == 0) bsum[blockIdx.x] = red[0];
}

__global__ void scan2_kernel(int* __restrict__ bsum, int* __restrict__ offs, int nb, int N){
  if (threadIdx.x == 0 && blockIdx.x == 0){
    int run = 0;
    for (int b = 0; b < nb; ++b){ int v = bsum[b]; bsum[b] = run; run += v; }
    offs[N] = run;
  }
}

__global__ __launch_bounds__(256) void scan3_kernel(const int* __restrict__ count,
                                                    const int* __restrict__ bsum,
                                                    int* __restrict__ offs,
                                                    int* __restrict__ cur, int N){
  __shared__ int red[256];
  const int t = threadIdx.x;
  int i0 = blockIdx.x * 2048 + t * 8;
  int v[8];
  int s = 0;
  #pragma unroll
  for (int r = 0; r < 8; ++r){ int i = i0 + r; v[r] = (i < N) ? count[i] : 0; s += v[r]; }
  red[t] = s;
  __syncthreads();
  #pragma unroll
  for (int off = 1; off < 256; off <<= 1){
    int tv = (t >= off) ? red[t - off] : 0;
    __syncthreads();
    red[t] += tv;
    __syncthreads();
  }
  int run = red[t] - s + bsum[blockIdx.x];
  #pragma unroll
  for (int r = 0; r < 8; ++r){
    int i = i0 + r;
    if (i < N){ offs[i] = run; cur[i] = run; }
    run += v[r];
  }
}

// se[slot] = (e, src), slots sorted by dst (CSR order)
__global__ void fill_kernel(const void* __restrict__ ei, const int* __restrict__ flag,
                            int* __restrict__ cur, int2* __restrict__ se, int E){
  const int is32 = *flag;
  for (long long e = (long long)blockIdx.x * 256 + threadIdx.x; e < E;
       e += (long long)gridDim.x * 256){
    int s = load_idx(ei, is32, (size_t)e);
    int d = load_idx(ei, is32, (size_t)((long long)E + e));
    int slot = atomicAdd(&cur[d], 1);
    se[slot] = make_int2((int)e, s);
  }
}

// ---------------- weight prep: fp32 row-major -> bf16 MFMA-fragment-linear --
// frag element q = ((ct*4+kt)*64 + lane)*8 + i  <->  W[ct*16+(lane&15)][kt*32+(lane>>4)*8+i]
struct WPtrs { const float* w[16]; };

__global__ __launch_bounds__(256) void prep_wfrag_kernel(WPtrs p, unsigned short* __restrict__ dst){
  const int m = blockIdx.x;
  const float* __restrict__ W = p.w[m];
  unsigned short* __restrict__ out = dst + (size_t)m * 16384;
  for (int q = threadIdx.x; q < 16384; q += 256){
    int i = q & 7, lane = (q >> 3) & 63, kt = (q >> 9) & 3, ct = q >> 11;
    int row = ct*16 + (lane & 15);
    int k   = kt*32 + (lane >> 4)*8 + i;
    out[q] = f2bf_u(W[row*128 + k]);
  }
}

// WG [128 f][64 k] -> bf16 fragments for the edge gate GEMM
__global__ __launch_bounds__(256) void prep_wgfrag_kernel(const float* __restrict__ WG,
                                                          unsigned short* __restrict__ dst){
  for (int q = blockIdx.x*256 + threadIdx.x; q < 8192; q += gridDim.x*256){
    int i = q & 7, lane = (q >> 3) & 63, kt = (q >> 9) & 1, nt = (q >> 10) & 3, half = q >> 12;
    int f = half*64 + nt*16 + (lane & 15);
    int k = kt*32 + (lane >> 4)*8 + i;
    dst[q] = f2bf_u(WG[(size_t)f*64 + k]);
  }
}

// ---------------- MFMA GEMM core: 128-row A tile (swizzled), K=128 --------
// A_s: bf16 [128][128], element (row,col) at row*128 + (col ^ ((row&7)<<3)).
// Bf: 16384 bf16 fragment-linear. acc[ct][q] = C[rbase+(lane>>4)*4+q][ct*16+(lane&15)]
__device__ __forceinline__ void mfma_gemm128s(const unsigned short* __restrict__ A_s,
                                              const unsigned short* __restrict__ Bf,
                                              int rbase, int lane, f32x4 acc[8]){
  #pragma unroll
  for (int ct = 0; ct < 8; ++ct) acc[ct] = (f32x4){0.f, 0.f, 0.f, 0.f};
  const int r  = rbase + (lane & 15);
  const int kg = lane >> 4;
  const int sw = (r & 7) << 3;
  #pragma unroll
  for (int kt = 0; kt < 4; ++kt){
    bf16x8 a = *(const bf16x8*)&A_s[r*128 + ((kt*32 + kg*8) ^ sw)];
    #pragma unroll
    for (int ct = 0; ct < 8; ++ct){
      bf16x8 b = *(const bf16x8*)&Bf[(size_t)((ct*4 + kt)*64 + lane)*8];
      acc[ct] = __builtin_amdgcn_mfma_f32_16x16x32_bf16(a, b, acc[ct], 0, 0, 0);
    }
  }
}

__device__ __forceinline__ void stage_bf512(unsigned short* __restrict__ Bf,
                                            const unsigned short* __restrict__ src, int t){
  #pragma unroll
  for (int it = 0; it < 4; ++it){
    int off = (it*512 + t) * 8;
    *(uint4*)&Bf[off] = *(const uint4*)&src[off];
  }
}

// ---------------- kernel 1: h = bf16(ssp(xa W_diff^T+b)), msged = ssp(xa W_same^T+b)
__global__ __launch_bounds__(512) void node_dual_kernel(
    const float* __restrict__ x, const unsigned short* __restrict__ wfrag,
    const float* __restrict__ bsame, const float* __restrict__ bdiff,
    unsigned short* __restrict__ hbf, float* __restrict__ msged, int N){
  __shared__ __align__(16) unsigned short A_s[128*128];
  __shared__ __align__(16) unsigned short Bf[16384];
  const int t = threadIdx.x, wv = t >> 6, lane = t & 63;
  const int kg = lane >> 4, c = lane & 15;
  const int row0 = blockIdx.x * 128;
  for (int q = t; q < 2048; q += 512){
    int row = q >> 4, c0 = (q & 15) * 8;
    float4 va = make_float4(0.f,0.f,0.f,0.f), vb = va;
    if (row0 + row < N){
      va = *(const float4*)&x[(size_t)(row0 + row)*128 + c0];
      vb = *(const float4*)&x[(size_t)(row0 + row)*128 + c0 + 4];
    }
    uint4 w;
    w.x = f2bf_u(ssp_f(va.x)) | ((unsigned)f2bf_u(ssp_f(va.y)) << 16);
    w.y = f2bf_u(ssp_f(va.z)) | ((unsigned)f2bf_u(ssp_f(va.w)) << 16);
    w.z = f2bf_u(ssp_f(vb.x)) | ((unsigned)f2bf_u(ssp_f(vb.y)) << 16);
    w.w = f2bf_u(ssp_f(vb.z)) | ((unsigned)f2bf_u(ssp_f(vb.w)) << 16);
    *(uint4*)&A_s[row*128 + (c0 ^ ((row & 7) << 3))] = w;
  }
  stage_bf512(Bf, wfrag, t);            // W_same
  __syncthreads();
  f32x4 acc[8];
  mfma_gemm128s(A_s, Bf, wv*16, lane, acc);
  #pragma unroll
  for (int ct = 0; ct < 8; ++ct){
    int col = ct*16 + c;
    float bv = bsame[col];
    #pragma unroll
    for (int q = 0; q < 4; ++q){
      int gr = row0 + wv*16 + kg*4 + q;
      if (gr < N) msged[(size_t)gr*128 + col] = ssp_f(acc[ct][q] + bv);
    }
  }
  __syncthreads();
  stage_bf512(Bf, wfrag + 16384, t);    // W_diff
  __syncthreads();
  mfma_gemm128s(A_s, Bf, wv*16, lane, acc);
  #pragma unroll
  for (int ct = 0; ct < 8; ++ct){
    int col = ct*16 + c;
    float bv = bdiff[col];
    #pragma unroll
    for (int q = 0; q < 4; ++q){
      int gr = row0 + wv*16 + kg*4 + q;
      if (gr < N) hbf[(size_t)gr*128 + col] = f2bf_u(ssp_f(acc[ct][q] + bv));
    }
  }
}

// ---------------- edge phase: batched MFMA gate + segmented reduce --------
// Wave owns a dst-aligned contiguous slot range (one feature half). Per 16-slot
// batch: gate = ea_rows @ WG^T (MFMA), P = gate*h[src] -> LDS, then a serial
// reduce with wave-uniform scalar boundary tracking from offs.
__global__ __launch_bounds__(256) void edge_mfma_kernel(
    const float* __restrict__ ea, const unsigned short* __restrict__ wgfrag,
    const unsigned short* __restrict__ h, const int2* __restrict__ se,
    const int* __restrict__ offs, float* __restrict__ msged, int N, int E, int KW){
  __shared__ float P_s[4][16][66];
  const int t = threadIdx.x, wv = t >> 6, lane = t & 63;
  const int kg = lane >> 4, c = lane & 15;
  const int gw = blockIdx.x * 4 + wv;
  const int half = gw & 1;
  const int widx = gw >> 1;
  if (widx >= KW) return;
  long long tt0 = (long long)widx * E / KW;
  long long tt1 = (long long)(widx + 1) * E / KW;
  int lo = 0, hi = N;
  while (lo < hi){ int mid = (lo + hi) >> 1; if ((long long)offs[mid] < tt0) lo = mid + 1; else hi = mid; }
  const int d_lo = lo;
  hi = N;
  while (lo < hi){ int mid = (lo + hi) >> 1; if ((long long)offs[mid] < tt1) lo = mid + 1; else hi = mid; }
  const int d_hi = lo;
  if (d_lo >= d_hi) return;
  const int s_beg = offs[d_lo], s_end = offs[d_hi];
  if (s_beg >= s_end) return;

  // preload this half's WG fragments (reused for all batches)
  bf16x8 bw[4][2];
  #pragma unroll
  for (int nt = 0; nt < 4; ++nt)
    #pragma unroll
    for (int kt = 0; kt < 2; ++kt)
      bw[nt][kt] = *(const bf16x8*)&wgfrag[(size_t)((((half*4+nt)*2+kt)*64)+lane)*8];

  // wave-uniform dst boundary tracking
  int d_cur = d_lo;
  int next_off = offs[d_cur + 1];
  while (next_off == s_beg && d_cur + 1 < d_hi){ ++d_cur; next_off = offs[d_cur + 1]; }

  float sum_v = 0.f;
  for (int p = s_beg; p < s_end; p += 16){
    const int nb = min(16, s_end - p);
    int2 s2 = se[p + min(c, nb-1)];                  // slot c metadata (e, src)

    // A fragments straight from global: row = slot c, k = kt*32 + kg*8 + i
    const float* ra = &ea[(size_t)s2.x * 64];
    float4 a00 = *(const float4*)&ra[kg*8];
    float4 a01 = *(const float4*)&ra[kg*8 + 4];
    float4 a10 = *(const float4*)&ra[32 + kg*8];
    float4 a11 = *(const float4*)&ra[32 + kg*8 + 4];

    // h values for acc elements (nt, q): row = src of slot kg*4+q
    int sv[4];
    #pragma unroll
    for (int q = 0; q < 4; ++q) sv[q] = __shfl(s2.y, kg*4 + q, 16);
    float hv[4][4];
    #pragma unroll
    for (int q = 0; q < 4; ++q){
      const unsigned short* hr = &h[(size_t)sv[q]*128 + half*64 + c];
      #pragma unroll
      for (int nt = 0; nt < 4; ++nt) hv[nt][q] = bf2f(hr[nt*16]);
    }

    bf16x8 af0, af1;
    unsigned short* w0 = (unsigned short*)&af0;
    unsigned short* w1 = (unsigned short*)&af1;
    w0[0]=f2bf_u(a00.x); w0[1]=f2bf_u(a00.y); w0[2]=f2bf_u(a00.z); w0[3]=f2bf_u(a00.w);
    w0[4]=f2bf_u(a01.x); w0[5]=f2bf_u(a01.y); w0[6]=f2bf_u(a01.z); w0[7]=f2bf_u(a01.w);
    w1[0]=f2bf_u(a10.x); w1[1]=f2bf_u(a10.y); w1[2]=f2bf_u(a10.z); w1[3]=f2bf_u(a10.w);
    w1[4]=f2bf_u(a11.x); w1[5]=f2bf_u(a11.y); w1[6]=f2bf_u(a11.z); w1[7]=f2bf_u(a11.w);

    f32x4 acc[4];
    #pragma unroll
    for (int nt = 0; nt < 4; ++nt) acc[nt] = (f32x4){0.f,0.f,0.f,0.f};
    #pragma unroll
    for (int nt = 0; nt < 4; ++nt){
      acc[nt] = __builtin_amdgcn_mfma_f32_16x16x32_bf16(af0, bw[nt][0], acc[nt], 0, 0, 0);
      acc[nt] = __builtin_amdgcn_mfma_f32_16x16x32_bf16(af1, bw[nt][1], acc[nt], 0, 0, 0);
    }

    // P = gate * h -> LDS [slot][f']  (f' = nt*16+c in 0..63)
    #pragma unroll
    for (int nt = 0; nt < 4; ++nt)
      #pragma unroll
      for (int q = 0; q < 4; ++q)
        P_s[wv][kg*4 + q][nt*16 + c] = acc[nt][q] * hv[nt][q];

    __builtin_amdgcn_s_waitcnt(0);   // P_s writes visible to own wave

    // segmented reduce; flush when slot j = p+i is last of dst d_cur
    for (int i = 0; i < nb; ++i){
      sum_v += P_s[wv][i][lane];
      if (p + i + 1 == next_off){
        msged[(size_t)d_cur*128 + half*64 + lane] += sum_v;   // owner-exclusive
        sum_v = 0.f;
        int old = next_off;
        do { ++d_cur; next_off = (d_cur < d_hi) ? offs[d_cur + 1] : 0x7FFFFFFF; }
        while (next_off == old);
      }
    }
  }
}

// ---------------- kernel 3: fused residual chain + final linear + skip ----
__global__ __launch_bounds__(512) void tail_kernel(
    const float* __restrict__ msged, const float* __restrict__ x, const float* __restrict__ u,
    const unsigned short* __restrict__ wfrag,
    const float* __restrict__ rb1, const float* __restrict__ rb2,
    const float* __restrict__ blast, float* __restrict__ out0, int N, int NRES){
  __shared__ __align__(16) unsigned short A_s[128*128];
  __shared__ __align__(16) unsigned short Bf[16384];
  const int t = threadIdx.x, wv = t >> 6, lane = t & 63;
  const int kg = lane >> 4, c = lane & 15;
  const int row0 = blockIdx.x * 128;

  float treg[8][4];
  #pragma unroll
  for (int ct = 0; ct < 8; ++ct)
    #pragma unroll
    for (int q = 0; q < 4; ++q){
      int gr = row0 + wv*16 + kg*4 + q;
      treg[ct][q] = (gr < N) ? msged[(size_t)gr*128 + ct*16 + c] : 0.f;
    }

  f32x4 acc[8];
  for (int l = 0; l < NRES; ++l){
    __syncthreads();                    // previous A_s/Bf readers done
    #pragma unroll
    for (int ct = 0; ct < 8; ++ct)
      #pragma unroll
      for (int q = 0; q < 4; ++q){
        int row = wv*16 + kg*4 + q, col = ct*16 + c;
        A_s[row*128 + (col ^ ((row & 7) << 3))] = f2bf_u(ssp_f(treg[ct][q]));
      }
    stage_bf512(Bf, wfrag + (size_t)(2 + 2*l)*16384, t);
    __syncthreads();
    mfma_gemm128s(A_s, Bf, wv*16, lane, acc);
    __syncthreads();                    // A_s/Bf reads done before overwrite
    #pragma unroll
    for (int ct = 0; ct < 8; ++ct){
      float bv = rb1[l*128 + ct*16 + c];
      #pragma unroll
      for (int q = 0; q < 4; ++q){
        int row = wv*16 + kg*4 + q, col = ct*16 + c;
        A_s[row*128 + (col ^ ((row & 7) << 3))] = f2bf_u(ssp_f(acc[ct][q] + bv));
      }
    }
    stage_bf512(Bf, wfrag + (size_t)(3 + 2*l)*16384, t);
    __syncthreads();
    mfma_gemm128s(A_s, Bf, wv*16, lane, acc);
    #pragma unroll
    for (int ct = 0; ct < 8; ++ct){
      float bv = rb2[l*128 + ct*16 + c];
      #pragma unroll
      for (int q = 0; q < 4; ++q) treg[ct][q] += acc[ct][q] + bv;
    }
  }
  __syncthreads();
  #pragma unroll
  for (int ct = 0; ct < 8; ++ct)
    #pragma unroll
    for (int q = 0; q < 4; ++q){
      int row = wv*16 + kg*4 + q, col = ct*16 + c;
      A_s[row*128 + (col ^ ((row & 7) << 3))] = f2bf_u(ssp_f(treg[ct][q]));
    }
  stage_bf512(Bf, wfrag + (size_t)(2 + 2*NRES)*16384, t);
  __syncthreads();
  mfma_gemm128s(A_s, Bf, wv*16, lane, acc);
  #pragma unroll
  for (int ct = 0; ct < 8; ++ct){
    int col = ct*16 + c;
    float bv = blast[col];
    float uv = u[col];
    #pragma unroll
    for (int q = 0; q < 4; ++q){
      int gr = row0 + wv*16 + kg*4 + q;
      if (gr < N){
        size_t idx = (size_t)gr*128 + col;
        out0[idx] = acc[ct][q] + bv + x[idx]*uv;
      }
    }
  }
}

extern "C" void kernel_launch(void* const* d_in, const int* in_sizes, int n_in,
                              void* d_out, int out_size, void* d_ws, size_t ws_size,
                              hipStream_t stream){
  const float* x     = (const float*)d_in[0];
  const void*  ei    = d_in[1];
  const float* ea    = (const float*)d_in[2];
  const float* Wsame = (const float*)d_in[3];
  const float* bsame = (const float*)d_in[4];
  const float* Wdiff = (const float*)d_in[5];
  const float* bdiff = (const float*)d_in[6];
  const float* WG    = (const float*)d_in[7];
  const float* rW1   = (const float*)d_in[8];
  const float* rb1   = (const float*)d_in[9];
  const float* rW2   = (const float*)d_in[10];
  const float* rb2   = (const float*)d_in[11];
  const float* Wlast = (const float*)d_in[12];
  const float* blast = (const float*)d_in[13];
  const float* u     = (const float*)d_in[14];

  const int N    = in_sizes[0] / 128;
  const int E    = in_sizes[1] / 2;
  int NRES = in_sizes[8] / (128*128);
  if (NRES > 6) NRES = 6;               // WPtrs capacity guard

  float* out0  = (float*)d_out;
  float* msged = (float*)d_out + (size_t)N * 128;   // second output, built in place

  auto align256 = [](size_t v){ return (v + 255) & ~(size_t)255; };
  const size_t o_h      = 256;
  const size_t o_count  = align256(o_h      + (size_t)N * 128 * 2);   // h is bf16
  const size_t o_off    = align256(o_count  + (size_t)N * 4);
  const size_t o_cur    = align256(o_off    + (size_t)(N + 1) * 4);
  const size_t o_se     = align256(o_cur    + (size_t)N * 4);
  const size_t o_bsum   = align256(o_se     + (size_t)E * 8);
  const size_t o_wfrag  = align256(o_bsum   + (size_t)4096 * 4);
  const size_t o_wgfrag = align256(o_wfrag  + (size_t)16 * 16384 * 2);

  int*   flag = (int*)d_ws;
  unsigned short* hbf = (unsigned short*)((char*)d_ws + o_h);
  int* count  = (int*)((char*)d_ws + o_count);
  int* offs   = (int*)((char*)d_ws + o_off);
  int* cur    = (int*)((char*)d_ws + o_cur);
  int2* se    = (int2*)((char*)d_ws + o_se);
  int* bsum   = (int*)((char*)d_ws + o_bsum);
  unsigned short* wfrag  = (unsigned short*)((char*)d_ws + o_wfrag);
  unsigned short* wgfrag = (unsigned short*)((char*)d_ws + o_wgfrag);
  (void)ws_size;

  const int nw = 3 + 2*NRES;            // same, diff, (W1,W2)*NRES, last
  WPtrs wp;
  wp.w[0] = Wsame;
  wp.w[1] = Wdiff;
  for (int l = 0; l < NRES; ++l){
    wp.w[2 + 2*l] = rW1 + (size_t)l*16384;
    wp.w[3 + 2*l] = rW2 + (size_t)l*16384;
  }
  wp.w[2 + 2*NRES] = Wlast;
  for (int i = nw; i < 16; ++i) wp.w[i] = Wlast;

  const int nb_node = (N + 127) / 128;
  const int nbk     = (N + 2047) / 2048;
  const int nb_edge = 2048;
  const int KW = nb_edge * 4 / 2;       // waves per feature-half

  detect_idx_kernel<<<1, 256, 0, stream>>>((const unsigned*)ei, flag);
  prep_wfrag_kernel<<<nw, 256, 0, stream>>>(wp, wfrag);
  prep_wgfrag_kernel<<<32, 256, 0, stream>>>(WG, wgfrag);
  node_dual_kernel<<<nb_node, 512, 0, stream>>>(x, wfrag, bsame, bdiff, hbf, msged, N);

  zero_int_kernel<<<(N + 255) / 256, 256, 0, stream>>>(count, N);
  hist_kernel<<<1024, 256, 0, stream>>>(ei, flag, count, E);
  scan1_kernel<<<nbk, 256, 0, stream>>>(count, bsum, N);
  scan2_kernel<<<1, 64, 0, stream>>>(bsum, offs, nbk, N);
  scan3_kernel<<<nbk, 256, 0, stream>>>(count, bsum, offs, cur, N);
  fill_kernel<<<1024, 256, 0, stream>>>(ei, flag, cur, se, E);

  edge_mfma_kernel<<<nb_edge, 256, 0, stream>>>(ea, wgfrag, hbf, se, offs, msged, N, E, KW);

  tail_kernel<<<nb_node, 512, 0, stream>>>(msged, x, u, wfrag, rb1, rb2, blast,
                                           out0, N, NRES);
}